// Round 2
// baseline (824.956 us; speedup 1.0000x reference)
//
#include <hip/hip_runtime.h>
#include <hip/hip_cooperative_groups.h>
#include <stdint.h>

namespace cg = cooperative_groups;

// GCN: 3x GraphConv (left norm) + heads, bf16 internal / fp32 accumulate.
// This revision: ONE cooperative mega-kernel (625 blocks x 256 thr, 3 blocks/CU
// co-resident) with grid.sync() between phases: zero -> hist -> scan-A ->
// scan-B -> build+feat -> L1 -> L2 -> L3+heads -> V. Parallel 625-way scan.
// Fallback to the multi-kernel path if cooperative launch is unsupported.

#define INF 128
#define HIDF 256
#define TMC 16    // rows per tile in mega kernel
#define TPB 256
#define TMF 32    // rows per tile in fallback fused kernels

typedef __attribute__((ext_vector_type(8))) short bf16x8;   // 8 bf16 (4 VGPRs)
typedef __attribute__((ext_vector_type(4))) float f32x4;

__device__ __forceinline__ float bf_lo(uint32_t u) {
    union { uint32_t i; float f; } x; x.i = u << 16; return x.f;
}
__device__ __forceinline__ float bf_hi(uint32_t u) {
    union { uint32_t i; float f; } x; x.i = u & 0xffff0000u; return x.f;
}
__device__ __forceinline__ uint16_t f2bf(float f) {   // round-to-nearest-even
    union { float f; uint32_t i; } x; x.f = f;
    uint32_t r = x.i + 0x7fffu + ((x.i >> 16) & 1u);
    return (uint16_t)(r >> 16);
}
__device__ __forceinline__ uint32_t pack2(float a, float b) {
    return (uint32_t)f2bf(a) | ((uint32_t)f2bf(b) << 16);
}

// =============================== mega kernel ===============================

struct KP {
    const float* features; const int* src; const int* dst;
    const float* W1; const float* b1; const float* W2; const float* b2;
    const float* W3; const float* b3; const float* Wp; const float* bp;
    const float* Wv; const float* bv;
    float* out;                       // pi [0..N), V at out[N]
    int* odeg; int* counts; int* cursor; float* colsum;
    int* offsets; int* ssrc; float* invd;
    uint16_t* fbf; uint16_t* h1; uint16_t* h2;
    uint16_t* W1s; uint16_t* W2s; uint16_t* W3s;
    int* partials;
    int N; int E;
};

__global__ __launch_bounds__(TPB, 3) void mega(KP P) {
    cg::grid_group grid = cg::this_grid();
    __shared__ uint16_t At[TMC * HIDF];   // 8 KB (layer tiles; L1 uses half)
    __shared__ int cnt_lds[64];
    __shared__ int red[TPB];
    __shared__ float pi_lds[TMC][4];

    const int tid = threadIdx.x;
    const int b = blockIdx.x;
    const int nb = gridDim.x;
    const int gsz = nb * TPB;
    const int gid = b * TPB + tid;
    const int lane = tid & 63, wid = tid >> 6;
    const int N = P.N, E = P.E;

    // ---- P0: zero counters ----
    for (int i = gid; i < N; i += gsz) { P.odeg[i] = 0; P.counts[i] = 0; P.cursor[i] = 0; }
    for (int i = gid; i < HIDF; i += gsz) P.colsum[i] = 0.f;
    grid.sync();

    // ---- P1: degree histograms ----
    for (int e = gid; e < E; e += gsz) {
        atomicAdd(&P.odeg[P.src[e]], 1);
        atomicAdd(&P.counts[P.dst[e]], 1);
    }
    grid.sync();

    // ---- P2: scan-A (per-block chunk sums) + inv_deg + weight swizzle ----
    const int CH = (N + nb - 1) / nb;          // 16 for N=10000, nb=625
    const int cstart = b * CH;
    if (tid < CH && tid < 64) {
        int idx = cstart + tid;
        int c = 0;
        if (idx < N) {
            c = P.counts[idx];
            int d = P.odeg[idx];
            P.invd[idx] = d > 0 ? 1.0f / (float)d : 0.0f;
        }
        cnt_lds[tid] = c;
    }
    for (int idx = gid; idx < INF * HIDF; idx += gsz) {
        int k = idx >> 8, n = idx & 255;
        P.W1s[((size_t)(k >> 5) * 256 + n) * 32 + (k & 31)] = f2bf(P.W1[idx]);
    }
    for (int idx = gid; idx < HIDF * HIDF; idx += gsz) {
        int k = idx >> 8, n = idx & 255;
        P.W2s[((size_t)(k >> 5) * 256 + n) * 32 + (k & 31)] = f2bf(P.W2[idx]);
    }
    for (int idx = gid; idx < HIDF * HIDF; idx += gsz) {
        int k = idx >> 8, n = idx & 255;
        P.W3s[((size_t)(k >> 5) * 256 + n) * 32 + (k & 31)] = f2bf(P.W3[idx]);
    }
    __syncthreads();
    if (tid == 0) {
        int s = 0;
        for (int i = 0; i < CH; i++) s += cnt_lds[i];
        P.partials[b] = s;
    }
    grid.sync();

    // ---- P3: exclusive base across blocks, write offsets ----
    {
        int v = 0;
        for (int j = tid; j < nb; j += TPB) if (j < b) v += P.partials[j];
        red[tid] = v;
        __syncthreads();
        for (int s = TPB >> 1; s > 0; s >>= 1) {
            if (tid < s) red[tid] += red[tid + s];
            __syncthreads();
        }
        if (tid == 0) {
            int run = red[0];
            for (int i = 0; i < CH; i++) {
                int idx = cstart + i;
                if (idx < N) { P.offsets[idx] = run; run += cnt_lds[i]; }
            }
            if (cstart < N && cstart + CH >= N) P.offsets[N] = run;
        }
    }
    grid.sync();

    // ---- P4: CSR edge build + feature convert (bf16 * inv_deg) ----
    for (int e = gid; e < E; e += gsz) {
        int d = P.dst[e];
        int pos = P.offsets[d] + atomicAdd(&P.cursor[d], 1);
        P.ssrc[pos] = P.src[e];
    }
    {
        int nc = N * (INF / 4);
        for (int idx = gid; idx < nc; idx += gsz) {
            int base4 = idx * 4;
            int row = base4 >> 7;
            float s = P.invd[row];
            float4 v = *(const float4*)&P.features[base4];
            ushort4 o;
            o.x = f2bf(v.x * s); o.y = f2bf(v.y * s);
            o.z = f2bf(v.z * s); o.w = f2bf(v.w * s);
            *(ushort4*)&P.fbf[base4] = o;
        }
    }
    grid.sync();

    const int ntiles = (N + TMC - 1) / TMC;

    // ---- P5: layer 1  (fbf 128-wide gather -> GEMM K=128 -> h1) ----
    for (int t = b; t < ntiles; t += nb) {
        {   // aggregate: wave quarters, 4 edges in flight
            const int q = lane >> 4, l16 = lane & 15;
            const size_t col = (size_t)l16 * 8;
            for (int nd = 0; nd < 4; nd++) {
                const int rt = wid * 4 + nd;
                const int node = t * TMC + rt;
                float a0 = 0, a1 = 0, a2 = 0, a3 = 0, a4 = 0, a5 = 0, a6 = 0, a7 = 0;
                if (node < N) {
                    const int beg = P.offsets[node], end = P.offsets[node + 1];
                    int e = beg + q;
                    for (; e + 4 < end; e += 8) {
                        int s0 = P.ssrc[e], s1 = P.ssrc[e + 4];
                        uint4 r0 = *(const uint4*)&P.fbf[(size_t)s0 * INF + col];
                        uint4 r1 = *(const uint4*)&P.fbf[(size_t)s1 * INF + col];
                        a0 += bf_lo(r0.x) + bf_lo(r1.x); a1 += bf_hi(r0.x) + bf_hi(r1.x);
                        a2 += bf_lo(r0.y) + bf_lo(r1.y); a3 += bf_hi(r0.y) + bf_hi(r1.y);
                        a4 += bf_lo(r0.z) + bf_lo(r1.z); a5 += bf_hi(r0.z) + bf_hi(r1.z);
                        a6 += bf_lo(r0.w) + bf_lo(r1.w); a7 += bf_hi(r0.w) + bf_hi(r1.w);
                    }
                    for (; e < end; e += 4) {
                        uint4 r = *(const uint4*)&P.fbf[(size_t)P.ssrc[e] * INF + col];
                        a0 += bf_lo(r.x); a1 += bf_hi(r.x); a2 += bf_lo(r.y); a3 += bf_hi(r.y);
                        a4 += bf_lo(r.z); a5 += bf_hi(r.z); a6 += bf_lo(r.w); a7 += bf_hi(r.w);
                    }
                }
                a0 += __shfl_down(a0, 16, 64); a1 += __shfl_down(a1, 16, 64);
                a2 += __shfl_down(a2, 16, 64); a3 += __shfl_down(a3, 16, 64);
                a4 += __shfl_down(a4, 16, 64); a5 += __shfl_down(a5, 16, 64);
                a6 += __shfl_down(a6, 16, 64); a7 += __shfl_down(a7, 16, 64);
                a0 += __shfl_down(a0, 32, 64); a1 += __shfl_down(a1, 32, 64);
                a2 += __shfl_down(a2, 32, 64); a3 += __shfl_down(a3, 32, 64);
                a4 += __shfl_down(a4, 32, 64); a5 += __shfl_down(a5, 32, 64);
                a6 += __shfl_down(a6, 32, 64); a7 += __shfl_down(a7, 32, 64);
                if (lane < 16) {
                    uint4 o;
                    o.x = pack2(a0, a1); o.y = pack2(a2, a3);
                    o.z = pack2(a4, a5); o.w = pack2(a6, a7);
                    const int byte = (rt * 256 + l16 * 16) ^ ((rt & 7) << 4);
                    *(uint4*)((char*)At + byte) = o;
                }
            }
        }
        __syncthreads();
        {   // GEMM: wave wid -> cols [wid*64, wid*64+64)
            const int quad = lane >> 4, l16 = lane & 15;
            const int n0 = wid * 64;
            const int xr = (l16 & 7) << 4;
            f32x4 acc0 = {0,0,0,0}, acc1 = {0,0,0,0}, acc2 = {0,0,0,0}, acc3 = {0,0,0,0};
#pragma unroll
            for (int p = 0; p < INF / 32; p++) {
                bf16x8 a = *(const bf16x8*)((const char*)At + ((l16 * 256 + p * 64 + quad * 16) ^ xr));
                bf16x8 b0 = *(const bf16x8*)(P.W1s + ((size_t)p * 256 + n0 + l16) * 32 + quad * 8);
                bf16x8 b1 = *(const bf16x8*)(P.W1s + ((size_t)p * 256 + n0 + 16 + l16) * 32 + quad * 8);
                bf16x8 b2 = *(const bf16x8*)(P.W1s + ((size_t)p * 256 + n0 + 32 + l16) * 32 + quad * 8);
                bf16x8 b3 = *(const bf16x8*)(P.W1s + ((size_t)p * 256 + n0 + 48 + l16) * 32 + quad * 8);
                acc0 = __builtin_amdgcn_mfma_f32_16x16x32_bf16(a, b0, acc0, 0, 0, 0);
                acc1 = __builtin_amdgcn_mfma_f32_16x16x32_bf16(a, b1, acc1, 0, 0, 0);
                acc2 = __builtin_amdgcn_mfma_f32_16x16x32_bf16(a, b2, acc2, 0, 0, 0);
                acc3 = __builtin_amdgcn_mfma_f32_16x16x32_bf16(a, b3, acc3, 0, 0, 0);
            }
            const int c0 = n0 + l16;
            const float bb0 = P.b1[c0], bb1 = P.b1[c0 + 16], bb2 = P.b1[c0 + 32], bb3 = P.b1[c0 + 48];
#pragma unroll
            for (int reg = 0; reg < 4; reg++) {
                int row = t * TMC + quad * 4 + reg;
                if (row < N) {
                    float s = P.invd[row];
                    P.h1[(size_t)row * 256 + c0     ] = f2bf(fmaxf(acc0[reg] + bb0, 0.f) * s);
                    P.h1[(size_t)row * 256 + c0 + 16] = f2bf(fmaxf(acc1[reg] + bb1, 0.f) * s);
                    P.h1[(size_t)row * 256 + c0 + 32] = f2bf(fmaxf(acc2[reg] + bb2, 0.f) * s);
                    P.h1[(size_t)row * 256 + c0 + 48] = f2bf(fmaxf(acc3[reg] + bb3, 0.f) * s);
                }
            }
        }
        __syncthreads();
    }
    grid.sync();

    // ---- P6: layer 2  (h1 256-wide gather -> GEMM K=256 -> h2) ----
    for (int t = b; t < ntiles; t += nb) {
        {   // aggregate: wave halves, 8-edge unroll
            const int half = lane >> 5, l32 = lane & 31;
            const size_t col = (size_t)l32 * 8;
            for (int nd = 0; nd < 4; nd++) {
                const int rt = wid * 4 + nd;
                const int node = t * TMC + rt;
                float a0 = 0, a1 = 0, a2 = 0, a3 = 0, a4 = 0, a5 = 0, a6 = 0, a7 = 0;
                if (node < N) {
                    const int beg = P.offsets[node], end = P.offsets[node + 1];
                    int e = beg + half;
                    for (; e + 6 < end; e += 8) {
                        int s0 = P.ssrc[e], s1 = P.ssrc[e + 2], s2 = P.ssrc[e + 4], s3 = P.ssrc[e + 6];
                        uint4 r0 = *(const uint4*)&P.h1[(size_t)s0 * 256 + col];
                        uint4 r1 = *(const uint4*)&P.h1[(size_t)s1 * 256 + col];
                        uint4 r2 = *(const uint4*)&P.h1[(size_t)s2 * 256 + col];
                        uint4 r3 = *(const uint4*)&P.h1[(size_t)s3 * 256 + col];
                        a0 += bf_lo(r0.x) + bf_lo(r1.x) + bf_lo(r2.x) + bf_lo(r3.x);
                        a1 += bf_hi(r0.x) + bf_hi(r1.x) + bf_hi(r2.x) + bf_hi(r3.x);
                        a2 += bf_lo(r0.y) + bf_lo(r1.y) + bf_lo(r2.y) + bf_lo(r3.y);
                        a3 += bf_hi(r0.y) + bf_hi(r1.y) + bf_hi(r2.y) + bf_hi(r3.y);
                        a4 += bf_lo(r0.z) + bf_lo(r1.z) + bf_lo(r2.z) + bf_lo(r3.z);
                        a5 += bf_hi(r0.z) + bf_hi(r1.z) + bf_hi(r2.z) + bf_hi(r3.z);
                        a6 += bf_lo(r0.w) + bf_lo(r1.w) + bf_lo(r2.w) + bf_lo(r3.w);
                        a7 += bf_hi(r0.w) + bf_hi(r1.w) + bf_hi(r2.w) + bf_hi(r3.w);
                    }
                    for (; e < end; e += 2) {
                        uint4 r = *(const uint4*)&P.h1[(size_t)P.ssrc[e] * 256 + col];
                        a0 += bf_lo(r.x); a1 += bf_hi(r.x); a2 += bf_lo(r.y); a3 += bf_hi(r.y);
                        a4 += bf_lo(r.z); a5 += bf_hi(r.z); a6 += bf_lo(r.w); a7 += bf_hi(r.w);
                    }
                }
                a0 += __shfl_down(a0, 32, 64); a1 += __shfl_down(a1, 32, 64);
                a2 += __shfl_down(a2, 32, 64); a3 += __shfl_down(a3, 32, 64);
                a4 += __shfl_down(a4, 32, 64); a5 += __shfl_down(a5, 32, 64);
                a6 += __shfl_down(a6, 32, 64); a7 += __shfl_down(a7, 32, 64);
                if (half == 0) {
                    uint4 o;
                    o.x = pack2(a0, a1); o.y = pack2(a2, a3);
                    o.z = pack2(a4, a5); o.w = pack2(a6, a7);
                    const int byte = (rt * 512 + l32 * 16) ^ ((rt & 7) << 4);
                    *(uint4*)((char*)At + byte) = o;
                }
            }
        }
        __syncthreads();
        {
            const int quad = lane >> 4, l16 = lane & 15;
            const int n0 = wid * 64;
            const int xr = (l16 & 7) << 4;
            f32x4 acc0 = {0,0,0,0}, acc1 = {0,0,0,0}, acc2 = {0,0,0,0}, acc3 = {0,0,0,0};
#pragma unroll
            for (int p = 0; p < HIDF / 32; p++) {
                bf16x8 a = *(const bf16x8*)((const char*)At + ((l16 * 512 + p * 64 + quad * 16) ^ xr));
                bf16x8 b0 = *(const bf16x8*)(P.W2s + ((size_t)p * 256 + n0 + l16) * 32 + quad * 8);
                bf16x8 b1 = *(const bf16x8*)(P.W2s + ((size_t)p * 256 + n0 + 16 + l16) * 32 + quad * 8);
                bf16x8 b2 = *(const bf16x8*)(P.W2s + ((size_t)p * 256 + n0 + 32 + l16) * 32 + quad * 8);
                bf16x8 b3 = *(const bf16x8*)(P.W2s + ((size_t)p * 256 + n0 + 48 + l16) * 32 + quad * 8);
                acc0 = __builtin_amdgcn_mfma_f32_16x16x32_bf16(a, b0, acc0, 0, 0, 0);
                acc1 = __builtin_amdgcn_mfma_f32_16x16x32_bf16(a, b1, acc1, 0, 0, 0);
                acc2 = __builtin_amdgcn_mfma_f32_16x16x32_bf16(a, b2, acc2, 0, 0, 0);
                acc3 = __builtin_amdgcn_mfma_f32_16x16x32_bf16(a, b3, acc3, 0, 0, 0);
            }
            const int c0 = n0 + l16;
            const float bb0 = P.b2[c0], bb1 = P.b2[c0 + 16], bb2 = P.b2[c0 + 32], bb3 = P.b2[c0 + 48];
#pragma unroll
            for (int reg = 0; reg < 4; reg++) {
                int row = t * TMC + quad * 4 + reg;
                if (row < N) {
                    float s = P.invd[row];
                    P.h2[(size_t)row * 256 + c0     ] = f2bf(fmaxf(acc0[reg] + bb0, 0.f) * s);
                    P.h2[(size_t)row * 256 + c0 + 16] = f2bf(fmaxf(acc1[reg] + bb1, 0.f) * s);
                    P.h2[(size_t)row * 256 + c0 + 32] = f2bf(fmaxf(acc2[reg] + bb2, 0.f) * s);
                    P.h2[(size_t)row * 256 + c0 + 48] = f2bf(fmaxf(acc3[reg] + bb3, 0.f) * s);
                }
            }
        }
        __syncthreads();
    }
    grid.sync();

    // ---- P7: layer 3 + both heads ----
    for (int t = b; t < ntiles; t += nb) {
        {   // aggregate h2 (identical to P6 aggregate)
            const int half = lane >> 5, l32 = lane & 31;
            const size_t col = (size_t)l32 * 8;
            for (int nd = 0; nd < 4; nd++) {
                const int rt = wid * 4 + nd;
                const int node = t * TMC + rt;
                float a0 = 0, a1 = 0, a2 = 0, a3 = 0, a4 = 0, a5 = 0, a6 = 0, a7 = 0;
                if (node < N) {
                    const int beg = P.offsets[node], end = P.offsets[node + 1];
                    int e = beg + half;
                    for (; e + 6 < end; e += 8) {
                        int s0 = P.ssrc[e], s1 = P.ssrc[e + 2], s2 = P.ssrc[e + 4], s3 = P.ssrc[e + 6];
                        uint4 r0 = *(const uint4*)&P.h2[(size_t)s0 * 256 + col];
                        uint4 r1 = *(const uint4*)&P.h2[(size_t)s1 * 256 + col];
                        uint4 r2 = *(const uint4*)&P.h2[(size_t)s2 * 256 + col];
                        uint4 r3 = *(const uint4*)&P.h2[(size_t)s3 * 256 + col];
                        a0 += bf_lo(r0.x) + bf_lo(r1.x) + bf_lo(r2.x) + bf_lo(r3.x);
                        a1 += bf_hi(r0.x) + bf_hi(r1.x) + bf_hi(r2.x) + bf_hi(r3.x);
                        a2 += bf_lo(r0.y) + bf_lo(r1.y) + bf_lo(r2.y) + bf_lo(r3.y);
                        a3 += bf_hi(r0.y) + bf_hi(r1.y) + bf_hi(r2.y) + bf_hi(r3.y);
                        a4 += bf_lo(r0.z) + bf_lo(r1.z) + bf_lo(r2.z) + bf_lo(r3.z);
                        a5 += bf_hi(r0.z) + bf_hi(r1.z) + bf_hi(r2.z) + bf_hi(r3.z);
                        a6 += bf_lo(r0.w) + bf_lo(r1.w) + bf_lo(r2.w) + bf_lo(r3.w);
                        a7 += bf_hi(r0.w) + bf_hi(r1.w) + bf_hi(r2.w) + bf_hi(r3.w);
                    }
                    for (; e < end; e += 2) {
                        uint4 r = *(const uint4*)&P.h2[(size_t)P.ssrc[e] * 256 + col];
                        a0 += bf_lo(r.x); a1 += bf_hi(r.x); a2 += bf_lo(r.y); a3 += bf_hi(r.y);
                        a4 += bf_lo(r.z); a5 += bf_hi(r.z); a6 += bf_lo(r.w); a7 += bf_hi(r.w);
                    }
                }
                a0 += __shfl_down(a0, 32, 64); a1 += __shfl_down(a1, 32, 64);
                a2 += __shfl_down(a2, 32, 64); a3 += __shfl_down(a3, 32, 64);
                a4 += __shfl_down(a4, 32, 64); a5 += __shfl_down(a5, 32, 64);
                a6 += __shfl_down(a6, 32, 64); a7 += __shfl_down(a7, 32, 64);
                if (half == 0) {
                    uint4 o;
                    o.x = pack2(a0, a1); o.y = pack2(a2, a3);
                    o.z = pack2(a4, a5); o.w = pack2(a6, a7);
                    const int byte = (rt * 512 + l32 * 16) ^ ((rt & 7) << 4);
                    *(uint4*)((char*)At + byte) = o;
                }
            }
        }
        __syncthreads();
        {
            const int quad = lane >> 4, l16 = lane & 15;
            const int n0 = wid * 64;
            const int xr = (l16 & 7) << 4;
            f32x4 acc0 = {0,0,0,0}, acc1 = {0,0,0,0}, acc2 = {0,0,0,0}, acc3 = {0,0,0,0};
#pragma unroll
            for (int p = 0; p < HIDF / 32; p++) {
                bf16x8 a = *(const bf16x8*)((const char*)At + ((l16 * 512 + p * 64 + quad * 16) ^ xr));
                bf16x8 b0 = *(const bf16x8*)(P.W3s + ((size_t)p * 256 + n0 + l16) * 32 + quad * 8);
                bf16x8 b1 = *(const bf16x8*)(P.W3s + ((size_t)p * 256 + n0 + 16 + l16) * 32 + quad * 8);
                bf16x8 b2 = *(const bf16x8*)(P.W3s + ((size_t)p * 256 + n0 + 32 + l16) * 32 + quad * 8);
                bf16x8 b3 = *(const bf16x8*)(P.W3s + ((size_t)p * 256 + n0 + 48 + l16) * 32 + quad * 8);
                acc0 = __builtin_amdgcn_mfma_f32_16x16x32_bf16(a, b0, acc0, 0, 0, 0);
                acc1 = __builtin_amdgcn_mfma_f32_16x16x32_bf16(a, b1, acc1, 0, 0, 0);
                acc2 = __builtin_amdgcn_mfma_f32_16x16x32_bf16(a, b2, acc2, 0, 0, 0);
                acc3 = __builtin_amdgcn_mfma_f32_16x16x32_bf16(a, b3, acc3, 0, 0, 0);
            }
            const int c0 = n0 + l16;
            const float bb0 = P.b3[c0], bb1 = P.b3[c0 + 16], bb2 = P.b3[c0 + 32], bb3 = P.b3[c0 + 48];
            const float wp0 = P.Wp[c0], wp1 = P.Wp[c0 + 16], wp2 = P.Wp[c0 + 32], wp3 = P.Wp[c0 + 48];
            float cs0 = 0.f, cs1 = 0.f, cs2 = 0.f, cs3 = 0.f;
#pragma unroll
            for (int reg = 0; reg < 4; reg++) {
                int row = t * TMC + quad * 4 + reg;
                bool ok = row < N;
                float v0 = acc0[reg] + bb0, v1 = acc1[reg] + bb1;
                float v2 = acc2[reg] + bb2, v3 = acc3[reg] + bb3;
                if (ok) { cs0 += v0; cs1 += v1; cs2 += v2; cs3 += v3; }
                float pp = v0 * wp0 + v1 * wp1 + v2 * wp2 + v3 * wp3;
#pragma unroll
                for (int m = 1; m < 16; m <<= 1) pp += __shfl_xor(pp, m, 64);
                if (l16 == 0 && ok) pi_lds[quad * 4 + reg][wid] = pp;
            }
            cs0 += __shfl_xor(cs0, 16, 64); cs0 += __shfl_xor(cs0, 32, 64);
            cs1 += __shfl_xor(cs1, 16, 64); cs1 += __shfl_xor(cs1, 32, 64);
            cs2 += __shfl_xor(cs2, 16, 64); cs2 += __shfl_xor(cs2, 32, 64);
            cs3 += __shfl_xor(cs3, 16, 64); cs3 += __shfl_xor(cs3, 32, 64);
            if (lane < 16) {
                atomicAdd(&P.colsum[n0 + lane], cs0);
                atomicAdd(&P.colsum[n0 + 16 + lane], cs1);
                atomicAdd(&P.colsum[n0 + 32 + lane], cs2);
                atomicAdd(&P.colsum[n0 + 48 + lane], cs3);
            }
        }
        __syncthreads();
        if (tid < TMC) {
            int row = t * TMC + tid;
            if (row < N)
                P.out[row] = pi_lds[tid][0] + pi_lds[tid][1] + pi_lds[tid][2] + pi_lds[tid][3]
                             + P.bp[0];
        }
        __syncthreads();
    }
    grid.sync();

    // ---- P8: V head ----
    if (b == 0 && tid < 64) {
        float v = 0.0f;
#pragma unroll
        for (int i = 0; i < 4; i++) v += P.colsum[tid + 64 * i] * P.Wv[tid + 64 * i];
#pragma unroll
        for (int o = 32; o > 0; o >>= 1) v += __shfl_down(v, o, 64);
        if (tid == 0) P.out[N] = v * (1.0f / (float)N) + P.bv[0];
    }
}

// ====================== fallback multi-kernel path ======================

__global__ void hist_prepw(const int* __restrict__ src, const int* __restrict__ dst,
                           int* __restrict__ odeg, int* __restrict__ counts,
                           const float* __restrict__ W1, const float* __restrict__ W2,
                           const float* __restrict__ W3,
                           uint16_t* __restrict__ W1s, uint16_t* __restrict__ W2s,
                           uint16_t* __restrict__ W3s, int E, int eb) {
    int b = blockIdx.x;
    if (b < eb) {
        int e = b * 256 + threadIdx.x;
        if (e < E) {
            atomicAdd(&odeg[src[e]], 1);
            atomicAdd(&counts[dst[e]], 1);
        }
        return;
    }
    int idx = (b - eb) * 256 + threadIdx.x;
    if (idx < INF * HIDF) {
        int k = idx >> 8, n = idx & 255;
        W1s[((size_t)(k >> 5) * 256 + n) * 32 + (k & 31)] = f2bf(W1[idx]);
        return;
    }
    idx -= INF * HIDF;
    if (idx < HIDF * HIDF) {
        int k = idx >> 8, n = idx & 255;
        W2s[((size_t)(k >> 5) * 256 + n) * 32 + (k & 31)] = f2bf(W2[idx]);
        return;
    }
    idx -= HIDF * HIDF;
    if (idx < HIDF * HIDF) {
        int k = idx >> 8, n = idx & 255;
        W3s[((size_t)(k >> 5) * 256 + n) * 32 + (k & 31)] = f2bf(W3[idx]);
    }
}

__global__ __launch_bounds__(1024) void scan_kernel(const int* __restrict__ counts,
                                                    int* __restrict__ offsets,
                                                    const int* __restrict__ odeg,
                                                    float* __restrict__ inv, int n) {
    __shared__ int partial[1024];
    int tid = threadIdx.x;
    int chunk = (n + 1023) / 1024;
    int start = tid * chunk;
    int s = 0;
    for (int i = 0; i < chunk; i++) {
        int idx = start + i;
        if (idx < n) {
            s += counts[idx];
            int d = odeg[idx];
            inv[idx] = d > 0 ? 1.0f / (float)d : 0.0f;
        }
    }
    partial[tid] = s;
    __syncthreads();
    for (int off = 1; off < 1024; off <<= 1) {
        int v = 0;
        if (tid >= off) v = partial[tid - off];
        __syncthreads();
        partial[tid] += v;
        __syncthreads();
    }
    int run = (tid > 0) ? partial[tid - 1] : 0;
    for (int i = 0; i < chunk; i++) {
        int idx = start + i;
        if (idx < n) { offsets[idx] = run; run += counts[idx]; }
    }
    if (tid == 1023) offsets[n] = partial[1023];
}

__global__ void build_feat(const int* __restrict__ src, const int* __restrict__ dst,
                           const int* __restrict__ offsets, int* __restrict__ cursor,
                           int* __restrict__ ssrc, const float* __restrict__ features,
                           const float* __restrict__ inv, uint16_t* __restrict__ fbf,
                           int E, int eb, int N) {
    int b = blockIdx.x;
    if (b < eb) {
        int e = b * 256 + threadIdx.x;
        if (e < E) {
            int d = dst[e];
            int pos = offsets[d] + atomicAdd(&cursor[d], 1);
            ssrc[pos] = src[e];
        }
        return;
    }
    int idx = (b - eb) * 256 + threadIdx.x;
    int nc = N * (INF / 4);
    if (idx < nc) {
        int base = idx * 4;
        int row = base >> 7;
        float s = inv[row];
        float4 v = *(const float4*)&features[base];
        ushort4 o;
        o.x = f2bf(v.x * s); o.y = f2bf(v.y * s);
        o.z = f2bf(v.z * s); o.w = f2bf(v.w * s);
        *(ushort4*)&fbf[base] = o;
    }
}

__global__ __launch_bounds__(512) void fused_l1(
    const uint16_t* __restrict__ hs, const int* __restrict__ offsets,
    const int* __restrict__ ssrc, const uint16_t* __restrict__ Bsw,
    const float* __restrict__ bias, const float* __restrict__ inv,
    uint16_t* __restrict__ C, int M) {
    __shared__ uint16_t At[TMF * INF];
    const int lane = threadIdx.x & 63, wid = threadIdx.x >> 6;
    {
        const int q = lane >> 4, l16 = lane & 15;
        const size_t col = (size_t)l16 * 8;
        for (int nd = 0; nd < 4; nd++) {
            const int rt = wid * 4 + nd;
            const int node = blockIdx.x * TMF + rt;
            float a0 = 0, a1 = 0, a2 = 0, a3 = 0, a4 = 0, a5 = 0, a6 = 0, a7 = 0;
            if (node < M) {
                const int beg = offsets[node], end = offsets[node + 1];
                int e = beg + q;
                for (; e + 4 < end; e += 8) {
                    int s0 = ssrc[e], s1 = ssrc[e + 4];
                    uint4 r0 = *(const uint4*)&hs[(size_t)s0 * INF + col];
                    uint4 r1 = *(const uint4*)&hs[(size_t)s1 * INF + col];
                    a0 += bf_lo(r0.x) + bf_lo(r1.x); a1 += bf_hi(r0.x) + bf_hi(r1.x);
                    a2 += bf_lo(r0.y) + bf_lo(r1.y); a3 += bf_hi(r0.y) + bf_hi(r1.y);
                    a4 += bf_lo(r0.z) + bf_lo(r1.z); a5 += bf_hi(r0.z) + bf_hi(r1.z);
                    a6 += bf_lo(r0.w) + bf_lo(r1.w); a7 += bf_hi(r0.w) + bf_hi(r1.w);
                }
                for (; e < end; e += 4) {
                    uint4 t = *(const uint4*)&hs[(size_t)ssrc[e] * INF + col];
                    a0 += bf_lo(t.x); a1 += bf_hi(t.x); a2 += bf_lo(t.y); a3 += bf_hi(t.y);
                    a4 += bf_lo(t.z); a5 += bf_hi(t.z); a6 += bf_lo(t.w); a7 += bf_hi(t.w);
                }
            }
            a0 += __shfl_down(a0, 16, 64); a1 += __shfl_down(a1, 16, 64);
            a2 += __shfl_down(a2, 16, 64); a3 += __shfl_down(a3, 16, 64);
            a4 += __shfl_down(a4, 16, 64); a5 += __shfl_down(a5, 16, 64);
            a6 += __shfl_down(a6, 16, 64); a7 += __shfl_down(a7, 16, 64);
            a0 += __shfl_down(a0, 32, 64); a1 += __shfl_down(a1, 32, 64);
            a2 += __shfl_down(a2, 32, 64); a3 += __shfl_down(a3, 32, 64);
            a4 += __shfl_down(a4, 32, 64); a5 += __shfl_down(a5, 32, 64);
            a6 += __shfl_down(a6, 32, 64); a7 += __shfl_down(a7, 32, 64);
            if (lane < 16) {
                uint4 o;
                o.x = pack2(a0, a1); o.y = pack2(a2, a3);
                o.z = pack2(a4, a5); o.w = pack2(a6, a7);
                const int byte = (rt * 256 + l16 * 16) ^ ((rt & 7) << 4);
                *(uint4*)((char*)At + byte) = o;
            }
        }
    }
    __syncthreads();
    const int quad = lane >> 4, l16 = lane & 15;
    const int n0 = wid * 32;
    const int xr = (l16 & 7) << 4;
    f32x4 acc00 = {0, 0, 0, 0}, acc01 = {0, 0, 0, 0};
    f32x4 acc10 = {0, 0, 0, 0}, acc11 = {0, 0, 0, 0};
#pragma unroll
    for (int p = 0; p < INF / 32; p++) {
        bf16x8 a0 = *(const bf16x8*)((const char*)At + ((l16 * 256 + p * 64 + quad * 16) ^ xr));
        bf16x8 a1 = *(const bf16x8*)((const char*)At + (((16 + l16) * 256 + p * 64 + quad * 16) ^ xr));
        bf16x8 b0 = *(const bf16x8*)(Bsw + ((size_t)p * 256 + n0 + l16) * 32 + quad * 8);
        bf16x8 b1 = *(const bf16x8*)(Bsw + ((size_t)p * 256 + n0 + 16 + l16) * 32 + quad * 8);
        acc00 = __builtin_amdgcn_mfma_f32_16x16x32_bf16(a0, b0, acc00, 0, 0, 0);
        acc01 = __builtin_amdgcn_mfma_f32_16x16x32_bf16(a0, b1, acc01, 0, 0, 0);
        acc10 = __builtin_amdgcn_mfma_f32_16x16x32_bf16(a1, b0, acc10, 0, 0, 0);
        acc11 = __builtin_amdgcn_mfma_f32_16x16x32_bf16(a1, b1, acc11, 0, 0, 0);
    }
    const int col0 = n0 + l16, col1 = col0 + 16;
    const float bv0 = bias[col0], bv1 = bias[col1];
#pragma unroll
    for (int reg = 0; reg < 4; reg++) {
        int row0 = blockIdx.x * TMF + quad * 4 + reg;
        int row1 = row0 + 16;
        if (row0 < M) {
            float s = inv[row0];
            C[(size_t)row0 * 256 + col0] = f2bf(fmaxf(acc00[reg] + bv0, 0.f) * s);
            C[(size_t)row0 * 256 + col1] = f2bf(fmaxf(acc01[reg] + bv1, 0.f) * s);
        }
        if (row1 < M) {
            float s = inv[row1];
            C[(size_t)row1 * 256 + col0] = f2bf(fmaxf(acc10[reg] + bv0, 0.f) * s);
            C[(size_t)row1 * 256 + col1] = f2bf(fmaxf(acc11[reg] + bv1, 0.f) * s);
        }
    }
}

__global__ __launch_bounds__(512) void fused_l2(
    const uint16_t* __restrict__ hs, const int* __restrict__ offsets,
    const int* __restrict__ ssrc, const uint16_t* __restrict__ Bsw,
    const float* __restrict__ bias, const float* __restrict__ inv,
    uint16_t* __restrict__ C, int M) {
    __shared__ uint16_t At[TMF * HIDF];
    const int lane = threadIdx.x & 63, wid = threadIdx.x >> 6;
    {
        const int half = lane >> 5, l32 = lane & 31;
        const size_t col = (size_t)l32 * 8;
        for (int nd = 0; nd < 4; nd++) {
            const int rt = wid * 4 + nd;
            const int node = blockIdx.x * TMF + rt;
            float a0 = 0, a1 = 0, a2 = 0, a3 = 0, a4 = 0, a5 = 0, a6 = 0, a7 = 0;
            if (node < M) {
                const int beg = offsets[node], end = offsets[node + 1];
                int e = beg + half;
                for (; e + 6 < end; e += 8) {
                    int s0 = ssrc[e], s1 = ssrc[e + 2], s2 = ssrc[e + 4], s3 = ssrc[e + 6];
                    uint4 r0 = *(const uint4*)&hs[(size_t)s0 * 256 + col];
                    uint4 r1 = *(const uint4*)&hs[(size_t)s1 * 256 + col];
                    uint4 r2 = *(const uint4*)&hs[(size_t)s2 * 256 + col];
                    uint4 r3 = *(const uint4*)&hs[(size_t)s3 * 256 + col];
                    a0 += bf_lo(r0.x) + bf_lo(r1.x) + bf_lo(r2.x) + bf_lo(r3.x);
                    a1 += bf_hi(r0.x) + bf_hi(r1.x) + bf_hi(r2.x) + bf_hi(r3.x);
                    a2 += bf_lo(r0.y) + bf_lo(r1.y) + bf_lo(r2.y) + bf_lo(r3.y);
                    a3 += bf_hi(r0.y) + bf_hi(r1.y) + bf_hi(r2.y) + bf_hi(r3.y);
                    a4 += bf_lo(r0.z) + bf_lo(r1.z) + bf_lo(r2.z) + bf_lo(r3.z);
                    a5 += bf_hi(r0.z) + bf_hi(r1.z) + bf_hi(r2.z) + bf_hi(r3.z);
                    a6 += bf_lo(r0.w) + bf_lo(r1.w) + bf_lo(r2.w) + bf_lo(r3.w);
                    a7 += bf_hi(r0.w) + bf_hi(r1.w) + bf_hi(r2.w) + bf_hi(r3.w);
                }
                for (; e < end; e += 2) {
                    uint4 t = *(const uint4*)&hs[(size_t)ssrc[e] * 256 + col];
                    a0 += bf_lo(t.x); a1 += bf_hi(t.x); a2 += bf_lo(t.y); a3 += bf_hi(t.y);
                    a4 += bf_lo(t.z); a5 += bf_hi(t.z); a6 += bf_lo(t.w); a7 += bf_hi(t.w);
                }
            }
            a0 += __shfl_down(a0, 32, 64); a1 += __shfl_down(a1, 32, 64);
            a2 += __shfl_down(a2, 32, 64); a3 += __shfl_down(a3, 32, 64);
            a4 += __shfl_down(a4, 32, 64); a5 += __shfl_down(a5, 32, 64);
            a6 += __shfl_down(a6, 32, 64); a7 += __shfl_down(a7, 32, 64);
            if (half == 0) {
                uint4 o;
                o.x = pack2(a0, a1); o.y = pack2(a2, a3);
                o.z = pack2(a4, a5); o.w = pack2(a6, a7);
                const int byte = (rt * 512 + l32 * 16) ^ ((rt & 7) << 4);
                *(uint4*)((char*)At + byte) = o;
            }
        }
    }
    __syncthreads();
    const int quad = lane >> 4, l16 = lane & 15;
    const int n0 = wid * 32;
    const int xr = (l16 & 7) << 4;
    f32x4 acc00 = {0, 0, 0, 0}, acc01 = {0, 0, 0, 0};
    f32x4 acc10 = {0, 0, 0, 0}, acc11 = {0, 0, 0, 0};
#pragma unroll
    for (int p = 0; p < HIDF / 32; p++) {
        bf16x8 a0 = *(const bf16x8*)((const char*)At + ((l16 * 512 + p * 64 + quad * 16) ^ xr));
        bf16x8 a1 = *(const bf16x8*)((const char*)At + (((16 + l16) * 512 + p * 64 + quad * 16) ^ xr));
        bf16x8 b0 = *(const bf16x8*)(Bsw + ((size_t)p * 256 + n0 + l16) * 32 + quad * 8);
        bf16x8 b1 = *(const bf16x8*)(Bsw + ((size_t)p * 256 + n0 + 16 + l16) * 32 + quad * 8);
        acc00 = __builtin_amdgcn_mfma_f32_16x16x32_bf16(a0, b0, acc00, 0, 0, 0);
        acc01 = __builtin_amdgcn_mfma_f32_16x16x32_bf16(a0, b1, acc01, 0, 0, 0);
        acc10 = __builtin_amdgcn_mfma_f32_16x16x32_bf16(a1, b0, acc10, 0, 0, 0);
        acc11 = __builtin_amdgcn_mfma_f32_16x16x32_bf16(a1, b1, acc11, 0, 0, 0);
    }
    const int col0 = n0 + l16, col1 = col0 + 16;
    const float bv0 = bias[col0], bv1 = bias[col1];
#pragma unroll
    for (int reg = 0; reg < 4; reg++) {
        int row0 = blockIdx.x * TMF + quad * 4 + reg;
        int row1 = row0 + 16;
        if (row0 < M) {
            float s = inv[row0];
            C[(size_t)row0 * 256 + col0] = f2bf(fmaxf(acc00[reg] + bv0, 0.f) * s);
            C[(size_t)row0 * 256 + col1] = f2bf(fmaxf(acc01[reg] + bv1, 0.f) * s);
        }
        if (row1 < M) {
            float s = inv[row1];
            C[(size_t)row1 * 256 + col0] = f2bf(fmaxf(acc10[reg] + bv0, 0.f) * s);
            C[(size_t)row1 * 256 + col1] = f2bf(fmaxf(acc11[reg] + bv1, 0.f) * s);
        }
    }
}

__global__ __launch_bounds__(512) void fused_l3(
    const uint16_t* __restrict__ hs, const int* __restrict__ offsets,
    const int* __restrict__ ssrc, const uint16_t* __restrict__ Bsw,
    const float* __restrict__ b3, const float* __restrict__ Wp,
    const float* __restrict__ bp, float* __restrict__ pi_out,
    float* __restrict__ colsum, int M) {
    __shared__ uint16_t At[TMF * HIDF];
    __shared__ float pi_lds[TMF][8];
    const int lane = threadIdx.x & 63, wid = threadIdx.x >> 6;
    {
        const int half = lane >> 5, l32 = lane & 31;
        const size_t col = (size_t)l32 * 8;
        for (int nd = 0; nd < 4; nd++) {
            const int rt = wid * 4 + nd;
            const int node = blockIdx.x * TMF + rt;
            float a0 = 0, a1 = 0, a2 = 0, a3 = 0, a4 = 0, a5 = 0, a6 = 0, a7 = 0;
            if (node < M) {
                const int beg = offsets[node], end = offsets[node + 1];
                int e = beg + half;
                for (; e + 6 < end; e += 8) {
                    int s0 = ssrc[e], s1 = ssrc[e + 2], s2 = ssrc[e + 4], s3 = ssrc[e + 6];
                    uint4 r0 = *(const uint4*)&hs[(size_t)s0 * 256 + col];
                    uint4 r1 = *(const uint4*)&hs[(size_t)s1 * 256 + col];
                    uint4 r2 = *(const uint4*)&hs[(size_t)s2 * 256 + col];
                    uint4 r3 = *(const uint4*)&hs[(size_t)s3 * 256 + col];
                    a0 += bf_lo(r0.x) + bf_lo(r1.x) + bf_lo(r2.x) + bf_lo(r3.x);
                    a1 += bf_hi(r0.x) + bf_hi(r1.x) + bf_hi(r2.x) + bf_hi(r3.x);
                    a2 += bf_lo(r0.y) + bf_lo(r1.y) + bf_lo(r2.y) + bf_lo(r3.y);
                    a3 += bf_hi(r0.y) + bf_hi(r1.y) + bf_hi(r2.y) + bf_hi(r3.y);
                    a4 += bf_lo(r0.z) + bf_lo(r1.z) + bf_lo(r2.z) + bf_lo(r3.z);
                    a5 += bf_hi(r0.z) + bf_hi(r1.z) + bf_hi(r2.z) + bf_hi(r3.z);
                    a6 += bf_lo(r0.w) + bf_lo(r1.w) + bf_lo(r2.w) + bf_lo(r3.w);
                    a7 += bf_hi(r0.w) + bf_hi(r1.w) + bf_hi(r2.w) + bf_hi(r3.w);
                }
                for (; e < end; e += 2) {
                    uint4 t = *(const uint4*)&hs[(size_t)ssrc[e] * 256 + col];
                    a0 += bf_lo(t.x); a1 += bf_hi(t.x); a2 += bf_lo(t.y); a3 += bf_hi(t.y);
                    a4 += bf_lo(t.z); a5 += bf_hi(t.z); a6 += bf_lo(t.w); a7 += bf_hi(t.w);
                }
            }
            a0 += __shfl_down(a0, 32, 64); a1 += __shfl_down(a1, 32, 64);
            a2 += __shfl_down(a2, 32, 64); a3 += __shfl_down(a3, 32, 64);
            a4 += __shfl_down(a4, 32, 64); a5 += __shfl_down(a5, 32, 64);
            a6 += __shfl_down(a6, 32, 64); a7 += __shfl_down(a7, 32, 64);
            if (half == 0) {
                uint4 o;
                o.x = pack2(a0, a1); o.y = pack2(a2, a3);
                o.z = pack2(a4, a5); o.w = pack2(a6, a7);
                const int byte = (rt * 512 + l32 * 16) ^ ((rt & 7) << 4);
                *(uint4*)((char*)At + byte) = o;
            }
        }
    }
    __syncthreads();
    const int quad = lane >> 4, l16 = lane & 15;
    const int n0 = wid * 32;
    const int xr = (l16 & 7) << 4;
    f32x4 acc00 = {0, 0, 0, 0}, acc01 = {0, 0, 0, 0};
    f32x4 acc10 = {0, 0, 0, 0}, acc11 = {0, 0, 0, 0};
#pragma unroll
    for (int p = 0; p < HIDF / 32; p++) {
        bf16x8 a0 = *(const bf16x8*)((const char*)At + ((l16 * 512 + p * 64 + quad * 16) ^ xr));
        bf16x8 a1 = *(const bf16x8*)((const char*)At + (((16 + l16) * 512 + p * 64 + quad * 16) ^ xr));
        bf16x8 b0 = *(const bf16x8*)(Bsw + ((size_t)p * 256 + n0 + l16) * 32 + quad * 8);
        bf16x8 b1 = *(const bf16x8*)(Bsw + ((size_t)p * 256 + n0 + 16 + l16) * 32 + quad * 8);
        acc00 = __builtin_amdgcn_mfma_f32_16x16x32_bf16(a0, b0, acc00, 0, 0, 0);
        acc01 = __builtin_amdgcn_mfma_f32_16x16x32_bf16(a0, b1, acc01, 0, 0, 0);
        acc10 = __builtin_amdgcn_mfma_f32_16x16x32_bf16(a1, b0, acc10, 0, 0, 0);
        acc11 = __builtin_amdgcn_mfma_f32_16x16x32_bf16(a1, b1, acc11, 0, 0, 0);
    }
    const int col0 = n0 + l16, col1 = col0 + 16;
    const float bv0 = b3[col0], bv1 = b3[col1];
    const float wp0 = Wp[col0], wp1 = Wp[col1];
    float cs0 = 0.f, cs1 = 0.f;
#pragma unroll
    for (int reg = 0; reg < 4; reg++) {
        int r0 = quad * 4 + reg, r1 = r0 + 16;
        int row0 = blockIdx.x * TMF + r0;
        int row1 = row0 + 16;
        bool ok0 = row0 < M, ok1 = row1 < M;
        float v00 = acc00[reg] + bv0, v01 = acc01[reg] + bv1;
        float v10 = acc10[reg] + bv0, v11 = acc11[reg] + bv1;
        if (ok0) { cs0 += v00; cs1 += v01; }
        if (ok1) { cs0 += v10; cs1 += v11; }
        float p0 = v00 * wp0 + v01 * wp1;
        float p1 = v10 * wp0 + v11 * wp1;
#pragma unroll
        for (int m = 1; m < 16; m <<= 1) {
            p0 += __shfl_xor(p0, m, 64);
            p1 += __shfl_xor(p1, m, 64);
        }
        if (l16 == 0) {
            pi_lds[r0][wid] = p0;
            pi_lds[r1][wid] = p1;
        }
    }
    cs0 += __shfl_xor(cs0, 16, 64); cs0 += __shfl_xor(cs0, 32, 64);
    cs1 += __shfl_xor(cs1, 16, 64); cs1 += __shfl_xor(cs1, 32, 64);
    if (quad == 0) {
        atomicAdd(&colsum[col0], cs0);
        atomicAdd(&colsum[col1], cs1);
    }
    __syncthreads();
    if (threadIdx.x < TMF) {
        int row = blockIdx.x * TMF + threadIdx.x;
        if (row < M) {
            float s = 0.f;
#pragma unroll
            for (int w = 0; w < 8; w++) s += pi_lds[threadIdx.x][w];
            pi_out[row] = s + bp[0];
        }
    }
}

__global__ void v_kernel(const float* __restrict__ colsum, const float* __restrict__ Wv,
                         const float* __restrict__ bv, float* __restrict__ out, float invN) {
    int lane = threadIdx.x;  // 64
    float v = 0.0f;
#pragma unroll
    for (int i = 0; i < 4; i++) v += colsum[lane + 64 * i] * Wv[lane + 64 * i];
#pragma unroll
    for (int o = 32; o > 0; o >>= 1) v += __shfl_down(v, o, 64);
    if (lane == 0) out[0] = v * invN + bv[0];
}

// ---------------- launch ----------------

extern "C" void kernel_launch(void* const* d_in, const int* in_sizes, int n_in,
                              void* d_out, int out_size, void* d_ws, size_t ws_size,
                              hipStream_t stream) {
    const float* features = (const float*)d_in[0];
    const int*   src      = (const int*)d_in[1];
    const int*   dst      = (const int*)d_in[2];
    const float* W1 = (const float*)d_in[3];
    const float* b1 = (const float*)d_in[4];
    const float* W2 = (const float*)d_in[5];
    const float* b2 = (const float*)d_in[6];
    const float* W3 = (const float*)d_in[7];
    const float* b3 = (const float*)d_in[8];
    const float* Wp = (const float*)d_in[9];
    const float* bp = (const float*)d_in[10];
    const float* Wv = (const float*)d_in[11];
    const float* bv = (const float*)d_in[12];
    float* out = (float*)d_out;

    const int N = in_sizes[0] / INF;   // 10000
    const int E = in_sizes[1];         // 320000

    char* p = (char*)d_ws;
    auto alloc = [&](size_t bytes) -> void* {
        void* r = (void*)p;
        p += (bytes + 511) & ~(size_t)511;
        return r;
    };
    int*      odeg    = (int*)alloc((size_t)N * 4);
    int*      counts  = (int*)alloc((size_t)N * 4);
    int*      cursor  = (int*)alloc((size_t)N * 4);
    float*    colsum  = (float*)alloc(HIDF * 4);
    size_t zero_bytes = (size_t)((char*)(colsum + HIDF) - (char*)d_ws);
    int*      offsets = (int*)alloc((size_t)(N + 1) * 4);
    int*      ssrc    = (int*)alloc((size_t)E * 4);
    float*    invd    = (float*)alloc((size_t)N * 4);
    uint16_t* fbf     = (uint16_t*)alloc((size_t)N * INF * 2);
    uint16_t* h1      = (uint16_t*)alloc((size_t)N * HIDF * 2);
    uint16_t* h2      = (uint16_t*)alloc((size_t)N * HIDF * 2);
    uint16_t* W1s     = (uint16_t*)alloc((size_t)INF * HIDF * 2);
    uint16_t* W2s     = (uint16_t*)alloc((size_t)HIDF * HIDF * 2);
    uint16_t* W3s     = (uint16_t*)alloc((size_t)HIDF * HIDF * 2);
    int*      partials= (int*)alloc((size_t)((N + TMC - 1) / TMC) * 4);

    const int ntiles = (N + TMC - 1) / TMC;   // 625

    KP hp;
    hp.features = features; hp.src = src; hp.dst = dst;
    hp.W1 = W1; hp.b1 = b1; hp.W2 = W2; hp.b2 = b2; hp.W3 = W3; hp.b3 = b3;
    hp.Wp = Wp; hp.bp = bp; hp.Wv = Wv; hp.bv = bv;
    hp.out = out;
    hp.odeg = odeg; hp.counts = counts; hp.cursor = cursor; hp.colsum = colsum;
    hp.offsets = offsets; hp.ssrc = ssrc; hp.invd = invd;
    hp.fbf = fbf; hp.h1 = h1; hp.h2 = h2;
    hp.W1s = W1s; hp.W2s = W2s; hp.W3s = W3s;
    hp.partials = partials;
    hp.N = N; hp.E = E;

    void* args[] = { &hp };
    hipError_t err = hipLaunchCooperativeKernel((void*)mega, dim3(ntiles), dim3(TPB),
                                                args, 0, stream);
    if (err != hipSuccess) {
        (void)hipGetLastError();   // clear sticky error, fall back
        hipMemsetAsync(d_ws, 0, zero_bytes, stream);
        const int eb = (E + 255) / 256;
        const int wb = (INF * HIDF + 2 * HIDF * HIDF + 255) / 256;
        hist_prepw<<<eb + wb, 256, 0, stream>>>(src, dst, odeg, counts,
                                                W1, W2, W3, W1s, W2s, W3s, E, eb);
        scan_kernel<<<1, 1024, 0, stream>>>(counts, offsets, odeg, invd, N);
        const int fb = (N * (INF / 4) + 255) / 256;
        build_feat<<<eb + fb, 256, 0, stream>>>(src, dst, offsets, cursor, ssrc,
                                                features, invd, fbf, E, eb, N);
        const int nblk = (N + TMF - 1) / TMF;
        fused_l1<<<nblk, 512, 0, stream>>>(fbf, offsets, ssrc, W1s, b1, invd, h1, N);
        fused_l2<<<nblk, 512, 0, stream>>>(h1, offsets, ssrc, W2s, b2, invd, h2, N);
        fused_l3<<<nblk, 512, 0, stream>>>(h2, offsets, ssrc, W3s, b3, Wp, bp, out, colsum, N);
        v_kernel<<<1, 64, 0, stream>>>(colsum, Wv, bv, out + N, 1.0f / (float)N);
    }
}

// Round 3
// 555.032 us; speedup vs baseline: 1.4863x; 1.4863x over previous
//
#include <hip/hip_runtime.h>
#include <stdint.h>

// GCN: 3x GraphConv (left norm) + heads, bf16 internal / fp32 accumulate.
// This revision: fused layers with TM=8 tiles (1250 blocks x 512 thr -> one
// node per wave, round-0 gather parallelism) + scan folded into hist's last
// block + V head folded into L3's last block (ticket gates). 6 dispatches.

#define INF 128
#define HIDF 256
#define TM 8     // rows per fused block (one node per wave)

typedef __attribute__((ext_vector_type(8))) short bf16x8;   // 8 bf16 (4 VGPRs)
typedef __attribute__((ext_vector_type(4))) float f32x4;

__device__ __forceinline__ float bf_lo(uint32_t u) {
    union { uint32_t i; float f; } x; x.i = u << 16; return x.f;
}
__device__ __forceinline__ float bf_hi(uint32_t u) {
    union { uint32_t i; float f; } x; x.i = u & 0xffff0000u; return x.f;
}
__device__ __forceinline__ uint16_t f2bf(float f) {   // round-to-nearest-even
    union { float f; uint32_t i; } x; x.f = f;
    uint32_t r = x.i + 0x7fffu + ((x.i >> 16) & 1u);
    return (uint16_t)(r >> 16);
}
__device__ __forceinline__ uint32_t pack2(float a, float b) {
    return (uint32_t)f2bf(a) | ((uint32_t)f2bf(b) << 16);
}

// ---------------- preprocessing ----------------
// blocks [0, eb): degree histograms. blocks [eb, ...): W swizzles.
// LAST finishing block (ticket gate) performs the scan + inv_deg inline,
// reading counts/odeg via device-coherent atomic reads.
__global__ void hist_prepw_scan(const int* __restrict__ src, const int* __restrict__ dst,
                                int* odeg, int* counts,
                                const float* __restrict__ W1, const float* __restrict__ W2,
                                const float* __restrict__ W3,
                                uint16_t* __restrict__ W1s, uint16_t* __restrict__ W2s,
                                uint16_t* __restrict__ W3s,
                                int* __restrict__ offsets, float* __restrict__ inv,
                                int* ticket, int E, int eb, int n) {
    const int b = blockIdx.x, tid = threadIdx.x;
    if (b < eb) {
        int e = b * 256 + tid;
        if (e < E) {
            atomicAdd(&odeg[src[e]], 1);
            atomicAdd(&counts[dst[e]], 1);
        }
    } else {
        int idx = (b - eb) * 256 + tid;
        if (idx < INF * HIDF) {
            int k = idx >> 8, nn = idx & 255;
            W1s[((size_t)(k >> 5) * 256 + nn) * 32 + (k & 31)] = f2bf(W1[idx]);
        } else {
            idx -= INF * HIDF;
            if (idx < HIDF * HIDF) {
                int k = idx >> 8, nn = idx & 255;
                W2s[((size_t)(k >> 5) * 256 + nn) * 32 + (k & 31)] = f2bf(W2[idx]);
            } else {
                idx -= HIDF * HIDF;
                if (idx < HIDF * HIDF) {
                    int k = idx >> 8, nn = idx & 255;
                    W3s[((size_t)(k >> 5) * 256 + nn) * 32 + (k & 31)] = f2bf(W3[idx]);
                }
            }
        }
    }
    // ---- gate: last finishing block runs the scan ----
    __threadfence();
    __shared__ int last;
    __shared__ int part[256];
    if (tid == 0) last = (atomicAdd(ticket, 1) == (int)gridDim.x - 1) ? 1 : 0;
    __syncthreads();
    if (!last) return;

    const int chunk = (n + 255) >> 8;      // 40 for n=10000
    const int start = tid * chunk;
    int s = 0;
    for (int i = 0; i < chunk; i++) {
        int idx = start + i;
        if (idx < n) {
            s += atomicAdd(&counts[idx], 0);           // coherent read
            int d = atomicAdd(&odeg[idx], 0);
            inv[idx] = d > 0 ? 1.0f / (float)d : 0.0f;
        }
    }
    part[tid] = s;
    __syncthreads();
    for (int off = 1; off < 256; off <<= 1) {
        int v = (tid >= off) ? part[tid - off] : 0;
        __syncthreads();
        part[tid] += v;
        __syncthreads();
    }
    int run = (tid > 0) ? part[tid - 1] : 0;
    for (int i = 0; i < chunk; i++) {
        int idx = start + i;
        if (idx < n) { offsets[idx] = run; run += atomicAdd(&counts[idx], 0); }
    }
    if (tid == 255) offsets[n] = part[255];
}

// blocks [0, eb): CSR edge build.  blocks [eb, ...): features -> bf16 * inv_deg.
__global__ void build_feat(const int* __restrict__ src, const int* __restrict__ dst,
                           const int* __restrict__ offsets, int* __restrict__ cursor,
                           int* __restrict__ ssrc, const float* __restrict__ features,
                           const float* __restrict__ inv, uint16_t* __restrict__ fbf,
                           int E, int eb, int N) {
    int b = blockIdx.x;
    if (b < eb) {
        int e = b * 256 + threadIdx.x;
        if (e < E) {
            int d = dst[e];
            int pos = offsets[d] + atomicAdd(&cursor[d], 1);
            ssrc[pos] = src[e];
        }
        return;
    }
    int idx = (b - eb) * 256 + threadIdx.x;
    int nc = N * (INF / 4);
    if (idx < nc) {
        int base = idx * 4;
        int row = base >> 7;                // /128
        float s = inv[row];
        float4 v = *(const float4*)&features[base];
        ushort4 o;
        o.x = f2bf(v.x * s); o.y = f2bf(v.y * s);
        o.z = f2bf(v.z * s); o.w = f2bf(v.w * s);
        *(ushort4*)&fbf[base] = o;
    }
}

// ---------------- fused layer 1: aggregate(128-wide) + GEMM K=128 ----------------
// 8 waves, ONE node per wave (max gather MLP). LDS A-tile 16 rows (top 8 zeroed),
// XOR-swizzled so MFMA ds_read_b128 is conflict-free.
__global__ __launch_bounds__(512) void fused_l1(
    const uint16_t* __restrict__ hs, const int* __restrict__ offsets,
    const int* __restrict__ ssrc, const uint16_t* __restrict__ Bsw,
    const float* __restrict__ bias, const float* __restrict__ inv,
    uint16_t* __restrict__ C, int M) {
    __shared__ uint16_t At[16 * INF];      // 4 KB, rows 8-15 zeroed
    const int tid = threadIdx.x;
    const int lane = tid & 63, wid = tid >> 6;
    if (tid < 128) {
        uint4 z = {0, 0, 0, 0};
        *(uint4*)((char*)At + 2048 + tid * 16) = z;
    }
    {   // aggregate: wave quarters, 4 edges in flight, node = blk*8 + wid
        const int q = lane >> 4, l16 = lane & 15;
        const size_t col = (size_t)l16 * 8;
        const int rt = wid;
        const int node = blockIdx.x * TM + rt;
        float a0 = 0, a1 = 0, a2 = 0, a3 = 0, a4 = 0, a5 = 0, a6 = 0, a7 = 0;
        if (node < M) {
            const int beg = offsets[node], end = offsets[node + 1];
            int e = beg + q;
            for (; e + 4 < end; e += 8) {
                int s0 = ssrc[e], s1 = ssrc[e + 4];
                uint4 r0 = *(const uint4*)&hs[(size_t)s0 * INF + col];
                uint4 r1 = *(const uint4*)&hs[(size_t)s1 * INF + col];
                a0 += bf_lo(r0.x) + bf_lo(r1.x); a1 += bf_hi(r0.x) + bf_hi(r1.x);
                a2 += bf_lo(r0.y) + bf_lo(r1.y); a3 += bf_hi(r0.y) + bf_hi(r1.y);
                a4 += bf_lo(r0.z) + bf_lo(r1.z); a5 += bf_hi(r0.z) + bf_hi(r1.z);
                a6 += bf_lo(r0.w) + bf_lo(r1.w); a7 += bf_hi(r0.w) + bf_hi(r1.w);
            }
            for (; e < end; e += 4) {
                uint4 t = *(const uint4*)&hs[(size_t)ssrc[e] * INF + col];
                a0 += bf_lo(t.x); a1 += bf_hi(t.x); a2 += bf_lo(t.y); a3 += bf_hi(t.y);
                a4 += bf_lo(t.z); a5 += bf_hi(t.z); a6 += bf_lo(t.w); a7 += bf_hi(t.w);
            }
        }
        a0 += __shfl_down(a0, 16, 64); a1 += __shfl_down(a1, 16, 64);
        a2 += __shfl_down(a2, 16, 64); a3 += __shfl_down(a3, 16, 64);
        a4 += __shfl_down(a4, 16, 64); a5 += __shfl_down(a5, 16, 64);
        a6 += __shfl_down(a6, 16, 64); a7 += __shfl_down(a7, 16, 64);
        a0 += __shfl_down(a0, 32, 64); a1 += __shfl_down(a1, 32, 64);
        a2 += __shfl_down(a2, 32, 64); a3 += __shfl_down(a3, 32, 64);
        a4 += __shfl_down(a4, 32, 64); a5 += __shfl_down(a5, 32, 64);
        a6 += __shfl_down(a6, 32, 64); a7 += __shfl_down(a7, 32, 64);
        if (lane < 16) {
            uint4 o;
            o.x = pack2(a0, a1); o.y = pack2(a2, a3);
            o.z = pack2(a4, a5); o.w = pack2(a6, a7);
            const int byte = (rt * 256 + l16 * 16) ^ ((rt & 7) << 4);
            *(uint4*)((char*)At + byte) = o;
        }
    }
    __syncthreads();
    // GEMM: wave wid handles cols [wid*32, wid*32+32); rows 0-7 valid
    const int quad = lane >> 4, l16 = lane & 15;
    const int n0 = wid * 32;
    const int xr = (l16 & 7) << 4;
    f32x4 acc00 = {0, 0, 0, 0}, acc01 = {0, 0, 0, 0};
#pragma unroll
    for (int p = 0; p < INF / 32; p++) {
        bf16x8 a0 = *(const bf16x8*)((const char*)At + ((l16 * 256 + p * 64 + quad * 16) ^ xr));
        bf16x8 b0 = *(const bf16x8*)(Bsw + ((size_t)p * 256 + n0 + l16) * 32 + quad * 8);
        bf16x8 b1 = *(const bf16x8*)(Bsw + ((size_t)p * 256 + n0 + 16 + l16) * 32 + quad * 8);
        acc00 = __builtin_amdgcn_mfma_f32_16x16x32_bf16(a0, b0, acc00, 0, 0, 0);
        acc01 = __builtin_amdgcn_mfma_f32_16x16x32_bf16(a0, b1, acc01, 0, 0, 0);
    }
    const int col0 = n0 + l16, col1 = col0 + 16;
    const float bv0 = bias[col0], bv1 = bias[col1];
#pragma unroll
    for (int reg = 0; reg < 4; reg++) {
        int r = quad * 4 + reg;
        if (r < 8) {
            int row = blockIdx.x * TM + r;
            if (row < M) {
                float s = inv[row];
                C[(size_t)row * 256 + col0] = f2bf(fmaxf(acc00[reg] + bv0, 0.f) * s);
                C[(size_t)row * 256 + col1] = f2bf(fmaxf(acc01[reg] + bv1, 0.f) * s);
            }
        }
    }
}

// ---------------- fused layer 2: aggregate(256-wide) + GEMM K=256 ----------------
__global__ __launch_bounds__(512) void fused_l2(
    const uint16_t* __restrict__ hs, const int* __restrict__ offsets,
    const int* __restrict__ ssrc, const uint16_t* __restrict__ Bsw,
    const float* __restrict__ bias, const float* __restrict__ inv,
    uint16_t* __restrict__ C, int M) {
    __shared__ uint16_t At[16 * HIDF];     // 8 KB, rows 8-15 zeroed
    const int tid = threadIdx.x;
    const int lane = tid & 63, wid = tid >> 6;
    if (tid < 256) {
        uint4 z = {0, 0, 0, 0};
        *(uint4*)((char*)At + 4096 + tid * 16) = z;
    }
    {   // aggregate: wave halves, 8-edge unroll, node = blk*8 + wid
        const int half = lane >> 5, l32 = lane & 31;
        const size_t col = (size_t)l32 * 8;
        const int rt = wid;
        const int node = blockIdx.x * TM + rt;
        float a0 = 0, a1 = 0, a2 = 0, a3 = 0, a4 = 0, a5 = 0, a6 = 0, a7 = 0;
        if (node < M) {
            const int beg = offsets[node], end = offsets[node + 1];
            int e = beg + half;
            for (; e + 6 < end; e += 8) {
                int s0 = ssrc[e], s1 = ssrc[e + 2], s2 = ssrc[e + 4], s3 = ssrc[e + 6];
                uint4 r0 = *(const uint4*)&hs[(size_t)s0 * 256 + col];
                uint4 r1 = *(const uint4*)&hs[(size_t)s1 * 256 + col];
                uint4 r2 = *(const uint4*)&hs[(size_t)s2 * 256 + col];
                uint4 r3 = *(const uint4*)&hs[(size_t)s3 * 256 + col];
                a0 += bf_lo(r0.x) + bf_lo(r1.x) + bf_lo(r2.x) + bf_lo(r3.x);
                a1 += bf_hi(r0.x) + bf_hi(r1.x) + bf_hi(r2.x) + bf_hi(r3.x);
                a2 += bf_lo(r0.y) + bf_lo(r1.y) + bf_lo(r2.y) + bf_lo(r3.y);
                a3 += bf_hi(r0.y) + bf_hi(r1.y) + bf_hi(r2.y) + bf_hi(r3.y);
                a4 += bf_lo(r0.z) + bf_lo(r1.z) + bf_lo(r2.z) + bf_lo(r3.z);
                a5 += bf_hi(r0.z) + bf_hi(r1.z) + bf_hi(r2.z) + bf_hi(r3.z);
                a6 += bf_lo(r0.w) + bf_lo(r1.w) + bf_lo(r2.w) + bf_lo(r3.w);
                a7 += bf_hi(r0.w) + bf_hi(r1.w) + bf_hi(r2.w) + bf_hi(r3.w);
            }
            for (; e < end; e += 2) {
                uint4 t = *(const uint4*)&hs[(size_t)ssrc[e] * 256 + col];
                a0 += bf_lo(t.x); a1 += bf_hi(t.x); a2 += bf_lo(t.y); a3 += bf_hi(t.y);
                a4 += bf_lo(t.z); a5 += bf_hi(t.z); a6 += bf_lo(t.w); a7 += bf_hi(t.w);
            }
        }
        a0 += __shfl_down(a0, 32, 64); a1 += __shfl_down(a1, 32, 64);
        a2 += __shfl_down(a2, 32, 64); a3 += __shfl_down(a3, 32, 64);
        a4 += __shfl_down(a4, 32, 64); a5 += __shfl_down(a5, 32, 64);
        a6 += __shfl_down(a6, 32, 64); a7 += __shfl_down(a7, 32, 64);
        if (half == 0) {
            uint4 o;
            o.x = pack2(a0, a1); o.y = pack2(a2, a3);
            o.z = pack2(a4, a5); o.w = pack2(a6, a7);
            const int byte = (rt * 512 + l32 * 16) ^ ((rt & 7) << 4);
            *(uint4*)((char*)At + byte) = o;
        }
    }
    __syncthreads();
    const int quad = lane >> 4, l16 = lane & 15;
    const int n0 = wid * 32;
    const int xr = (l16 & 7) << 4;
    f32x4 acc00 = {0, 0, 0, 0}, acc01 = {0, 0, 0, 0};
#pragma unroll
    for (int p = 0; p < HIDF / 32; p++) {
        bf16x8 a0 = *(const bf16x8*)((const char*)At + ((l16 * 512 + p * 64 + quad * 16) ^ xr));
        bf16x8 b0 = *(const bf16x8*)(Bsw + ((size_t)p * 256 + n0 + l16) * 32 + quad * 8);
        bf16x8 b1 = *(const bf16x8*)(Bsw + ((size_t)p * 256 + n0 + 16 + l16) * 32 + quad * 8);
        acc00 = __builtin_amdgcn_mfma_f32_16x16x32_bf16(a0, b0, acc00, 0, 0, 0);
        acc01 = __builtin_amdgcn_mfma_f32_16x16x32_bf16(a0, b1, acc01, 0, 0, 0);
    }
    const int col0 = n0 + l16, col1 = col0 + 16;
    const float bv0 = bias[col0], bv1 = bias[col1];
#pragma unroll
    for (int reg = 0; reg < 4; reg++) {
        int r = quad * 4 + reg;
        if (r < 8) {
            int row = blockIdx.x * TM + r;
            if (row < M) {
                float s = inv[row];
                C[(size_t)row * 256 + col0] = f2bf(fmaxf(acc00[reg] + bv0, 0.f) * s);
                C[(size_t)row * 256 + col1] = f2bf(fmaxf(acc01[reg] + bv1, 0.f) * s);
            }
        }
    }
}

// ---------------- fused layer 3 + both heads + V (last-block gate) ----------------
__global__ __launch_bounds__(512) void fused_l3(
    const uint16_t* __restrict__ hs, const int* __restrict__ offsets,
    const int* __restrict__ ssrc, const uint16_t* __restrict__ Bsw,
    const float* __restrict__ b3, const float* __restrict__ Wp,
    const float* __restrict__ bp, const float* __restrict__ Wv,
    const float* __restrict__ bvp, float* __restrict__ pi_out,
    float* colsum, int* ticket, int M) {
    __shared__ uint16_t At[16 * HIDF];     // 8 KB, rows 8-15 zeroed
    __shared__ float pi_lds[TM][8];
    __shared__ int last;
    const int tid = threadIdx.x;
    const int lane = tid & 63, wid = tid >> 6;
    if (tid < 256) {
        uint4 z = {0, 0, 0, 0};
        *(uint4*)((char*)At + 4096 + tid * 16) = z;
    }
    {   // aggregate h2 (identical structure to l2)
        const int half = lane >> 5, l32 = lane & 31;
        const size_t col = (size_t)l32 * 8;
        const int rt = wid;
        const int node = blockIdx.x * TM + rt;
        float a0 = 0, a1 = 0, a2 = 0, a3 = 0, a4 = 0, a5 = 0, a6 = 0, a7 = 0;
        if (node < M) {
            const int beg = offsets[node], end = offsets[node + 1];
            int e = beg + half;
            for (; e + 6 < end; e += 8) {
                int s0 = ssrc[e], s1 = ssrc[e + 2], s2 = ssrc[e + 4], s3 = ssrc[e + 6];
                uint4 r0 = *(const uint4*)&hs[(size_t)s0 * 256 + col];
                uint4 r1 = *(const uint4*)&hs[(size_t)s1 * 256 + col];
                uint4 r2 = *(const uint4*)&hs[(size_t)s2 * 256 + col];
                uint4 r3 = *(const uint4*)&hs[(size_t)s3 * 256 + col];
                a0 += bf_lo(r0.x) + bf_lo(r1.x) + bf_lo(r2.x) + bf_lo(r3.x);
                a1 += bf_hi(r0.x) + bf_hi(r1.x) + bf_hi(r2.x) + bf_hi(r3.x);
                a2 += bf_lo(r0.y) + bf_lo(r1.y) + bf_lo(r2.y) + bf_lo(r3.y);
                a3 += bf_hi(r0.y) + bf_hi(r1.y) + bf_hi(r2.y) + bf_hi(r3.y);
                a4 += bf_lo(r0.z) + bf_lo(r1.z) + bf_lo(r2.z) + bf_lo(r3.z);
                a5 += bf_hi(r0.z) + bf_hi(r1.z) + bf_hi(r2.z) + bf_hi(r3.z);
                a6 += bf_lo(r0.w) + bf_lo(r1.w) + bf_lo(r2.w) + bf_lo(r3.w);
                a7 += bf_hi(r0.w) + bf_hi(r1.w) + bf_hi(r2.w) + bf_hi(r3.w);
            }
            for (; e < end; e += 2) {
                uint4 t = *(const uint4*)&hs[(size_t)ssrc[e] * 256 + col];
                a0 += bf_lo(t.x); a1 += bf_hi(t.x); a2 += bf_lo(t.y); a3 += bf_hi(t.y);
                a4 += bf_lo(t.z); a5 += bf_hi(t.z); a6 += bf_lo(t.w); a7 += bf_hi(t.w);
            }
        }
        a0 += __shfl_down(a0, 32, 64); a1 += __shfl_down(a1, 32, 64);
        a2 += __shfl_down(a2, 32, 64); a3 += __shfl_down(a3, 32, 64);
        a4 += __shfl_down(a4, 32, 64); a5 += __shfl_down(a5, 32, 64);
        a6 += __shfl_down(a6, 32, 64); a7 += __shfl_down(a7, 32, 64);
        if (half == 0) {
            uint4 o;
            o.x = pack2(a0, a1); o.y = pack2(a2, a3);
            o.z = pack2(a4, a5); o.w = pack2(a6, a7);
            const int byte = (rt * 512 + l32 * 16) ^ ((rt & 7) << 4);
            *(uint4*)((char*)At + byte) = o;
        }
    }
    __syncthreads();
    const int quad = lane >> 4, l16 = lane & 15;
    const int n0 = wid * 32;
    const int xr = (l16 & 7) << 4;
    f32x4 acc00 = {0, 0, 0, 0}, acc01 = {0, 0, 0, 0};
#pragma unroll
    for (int p = 0; p < HIDF / 32; p++) {
        bf16x8 a0 = *(const bf16x8*)((const char*)At + ((l16 * 512 + p * 64 + quad * 16) ^ xr));
        bf16x8 b0 = *(const bf16x8*)(Bsw + ((size_t)p * 256 + n0 + l16) * 32 + quad * 8);
        bf16x8 b1 = *(const bf16x8*)(Bsw + ((size_t)p * 256 + n0 + 16 + l16) * 32 + quad * 8);
        acc00 = __builtin_amdgcn_mfma_f32_16x16x32_bf16(a0, b0, acc00, 0, 0, 0);
        acc01 = __builtin_amdgcn_mfma_f32_16x16x32_bf16(a0, b1, acc01, 0, 0, 0);
    }
    const int col0 = n0 + l16, col1 = col0 + 16;
    const float bv0 = b3[col0], bv1 = b3[col1];
    const float wp0 = Wp[col0], wp1 = Wp[col1];
    float cs0 = 0.f, cs1 = 0.f;
#pragma unroll
    for (int reg = 0; reg < 4; reg++) {
        int r = quad * 4 + reg;
        int row = blockIdx.x * TM + r;
        bool ok = (r < 8) && (row < M);
        float v00 = acc00[reg] + bv0, v01 = acc01[reg] + bv1;
        if (ok) { cs0 += v00; cs1 += v01; }
        float p0 = v00 * wp0 + v01 * wp1;
#pragma unroll
        for (int m = 1; m < 16; m <<= 1) p0 += __shfl_xor(p0, m, 64);
        if (l16 == 0 && ok) pi_lds[r][wid] = p0;
    }
    cs0 += __shfl_xor(cs0, 16, 64); cs0 += __shfl_xor(cs0, 32, 64);
    cs1 += __shfl_xor(cs1, 16, 64); cs1 += __shfl_xor(cs1, 32, 64);
    if (quad == 0) {
        atomicAdd(&colsum[col0], cs0);
        atomicAdd(&colsum[col1], cs1);
    }
    __syncthreads();
    if (tid < TM) {
        int row = blockIdx.x * TM + tid;
        if (row < M) {
            float s = 0.f;
#pragma unroll
            for (int w = 0; w < 8; w++) s += pi_lds[tid][w];
            pi_out[row] = s + bp[0];
        }
    }
    // ---- V head: last finishing block ----
    __threadfence();
    if (tid == 0) last = (atomicAdd(ticket, 1) == (int)gridDim.x - 1) ? 1 : 0;
    __syncthreads();
    if (last && tid < 64) {
        float v = 0.0f;
#pragma unroll
        for (int i = 0; i < 4; i++)
            v += atomicAdd(&colsum[tid + 64 * i], 0.f) * Wv[tid + 64 * i];
#pragma unroll
        for (int o = 32; o > 0; o >>= 1) v += __shfl_down(v, o, 64);
        if (tid == 0) pi_out[M] = v * (1.0f / (float)M) + bvp[0];
    }
}

// ---------------- launch ----------------

extern "C" void kernel_launch(void* const* d_in, const int* in_sizes, int n_in,
                              void* d_out, int out_size, void* d_ws, size_t ws_size,
                              hipStream_t stream) {
    const float* features = (const float*)d_in[0];
    const int*   src      = (const int*)d_in[1];
    const int*   dst      = (const int*)d_in[2];
    const float* W1 = (const float*)d_in[3];
    const float* b1 = (const float*)d_in[4];
    const float* W2 = (const float*)d_in[5];
    const float* b2 = (const float*)d_in[6];
    const float* W3 = (const float*)d_in[7];
    const float* b3 = (const float*)d_in[8];
    const float* Wp = (const float*)d_in[9];
    const float* bp = (const float*)d_in[10];
    const float* Wv = (const float*)d_in[11];
    const float* bv = (const float*)d_in[12];
    float* out = (float*)d_out;

    const int N = in_sizes[0] / INF;   // 10000
    const int E = in_sizes[1];         // 320000

    char* p = (char*)d_ws;
    auto alloc = [&](size_t bytes) -> void* {
        void* r = (void*)p;
        p += (bytes + 511) & ~(size_t)511;
        return r;
    };
    // zero-region first (single memset): odeg, counts, cursor, colsum, tickets
    int*      odeg    = (int*)alloc((size_t)N * 4);
    int*      counts  = (int*)alloc((size_t)N * 4);
    int*      cursor  = (int*)alloc((size_t)N * 4);
    float*    colsum  = (float*)alloc(HIDF * 4);
    int*      tickets = (int*)alloc(2 * 4);
    size_t zero_bytes = (size_t)(p - (char*)d_ws);
    // rest
    int*      offsets = (int*)alloc((size_t)(N + 1) * 4);
    int*      ssrc    = (int*)alloc((size_t)E * 4);
    float*    invd    = (float*)alloc((size_t)N * 4);
    uint16_t* fbf     = (uint16_t*)alloc((size_t)N * INF * 2);
    uint16_t* h1      = (uint16_t*)alloc((size_t)N * HIDF * 2);
    uint16_t* h2      = (uint16_t*)alloc((size_t)N * HIDF * 2);
    uint16_t* W1s     = (uint16_t*)alloc((size_t)INF * HIDF * 2);
    uint16_t* W2s     = (uint16_t*)alloc((size_t)HIDF * HIDF * 2);
    uint16_t* W3s     = (uint16_t*)alloc((size_t)HIDF * HIDF * 2);

    hipMemsetAsync(d_ws, 0, zero_bytes, stream);

    const int eb = (E + 255) / 256;
    const int wb = (INF * HIDF + 2 * HIDF * HIDF + 255) / 256;
    hist_prepw_scan<<<eb + wb, 256, 0, stream>>>(src, dst, odeg, counts,
                                                 W1, W2, W3, W1s, W2s, W3s,
                                                 offsets, invd, &tickets[0], E, eb, N);
    const int fb = (N * (INF / 4) + 255) / 256;
    build_feat<<<eb + fb, 256, 0, stream>>>(src, dst, offsets, cursor, ssrc,
                                            features, invd, fbf, E, eb, N);

    const int nblk = (N + TM - 1) / TM;   // 1250
    fused_l1<<<nblk, 512, 0, stream>>>(fbf, offsets, ssrc, W1s, b1, invd, h1, N);
    fused_l2<<<nblk, 512, 0, stream>>>(h1, offsets, ssrc, W2s, b2, invd, h2, N);
    fused_l3<<<nblk, 512, 0, stream>>>(h2, offsets, ssrc, W3s, b3, Wp, bp,
                                       Wv, bv, out, colsum, &tickets[1], N);
}

// Round 4
// 247.932 us; speedup vs baseline: 3.3273x; 2.2386x over previous
//
#include <hip/hip_runtime.h>
#include <stdint.h>

// GCN: 3x GraphConv (left norm) + heads, bf16 internal / fp32 accumulate.
// This revision: round-1 skeleton (NO device fences / ticket gates -- those
// cost ~200us each on gfx950 due to per-XCD L2 writeback) + TM=8 fused layers
// (one node per wave, 1250 blocks x 512 thr = max gather parallelism, no ab
// round-trip). 7 dispatches.

#define INF 128
#define HIDF 256
#define TM 8     // rows per fused block (one node per wave)

typedef __attribute__((ext_vector_type(8))) short bf16x8;   // 8 bf16 (4 VGPRs)
typedef __attribute__((ext_vector_type(4))) float f32x4;

__device__ __forceinline__ float bf_lo(uint32_t u) {
    union { uint32_t i; float f; } x; x.i = u << 16; return x.f;
}
__device__ __forceinline__ float bf_hi(uint32_t u) {
    union { uint32_t i; float f; } x; x.i = u & 0xffff0000u; return x.f;
}
__device__ __forceinline__ uint16_t f2bf(float f) {   // round-to-nearest-even
    union { float f; uint32_t i; } x; x.f = f;
    uint32_t r = x.i + 0x7fffu + ((x.i >> 16) & 1u);
    return (uint16_t)(r >> 16);
}
__device__ __forceinline__ uint32_t pack2(float a, float b) {
    return (uint32_t)f2bf(a) | ((uint32_t)f2bf(b) << 16);
}

// ---------------- preprocessing ----------------

// blocks [0, eb): degree histograms.  blocks [eb, ...): W1/W2/W3 swizzle.
// Bsw layout: [k/32][n][k%32]
__global__ void hist_prepw(const int* __restrict__ src, const int* __restrict__ dst,
                           int* __restrict__ odeg, int* __restrict__ counts,
                           const float* __restrict__ W1, const float* __restrict__ W2,
                           const float* __restrict__ W3,
                           uint16_t* __restrict__ W1s, uint16_t* __restrict__ W2s,
                           uint16_t* __restrict__ W3s, int E, int eb) {
    int b = blockIdx.x;
    if (b < eb) {
        int e = b * 256 + threadIdx.x;
        if (e < E) {
            atomicAdd(&odeg[src[e]], 1);
            atomicAdd(&counts[dst[e]], 1);
        }
        return;
    }
    int idx = (b - eb) * 256 + threadIdx.x;
    if (idx < INF * HIDF) {
        int k = idx >> 8, n = idx & 255;
        W1s[((size_t)(k >> 5) * 256 + n) * 32 + (k & 31)] = f2bf(W1[idx]);
        return;
    }
    idx -= INF * HIDF;
    if (idx < HIDF * HIDF) {
        int k = idx >> 8, n = idx & 255;
        W2s[((size_t)(k >> 5) * 256 + n) * 32 + (k & 31)] = f2bf(W2[idx]);
        return;
    }
    idx -= HIDF * HIDF;
    if (idx < HIDF * HIDF) {
        int k = idx >> 8, n = idx & 255;
        W3s[((size_t)(k >> 5) * 256 + n) * 32 + (k & 31)] = f2bf(W3[idx]);
    }
}

// scan of counts -> offsets[0..n]; also computes inv_deg
__global__ __launch_bounds__(1024) void scan_kernel(const int* __restrict__ counts,
                                                    int* __restrict__ offsets,
                                                    const int* __restrict__ odeg,
                                                    float* __restrict__ inv, int n) {
    __shared__ int partial[1024];
    int tid = threadIdx.x;
    int chunk = (n + 1023) / 1024;
    int start = tid * chunk;
    int s = 0;
    for (int i = 0; i < chunk; i++) {
        int idx = start + i;
        if (idx < n) {
            s += counts[idx];
            int d = odeg[idx];
            inv[idx] = d > 0 ? 1.0f / (float)d : 0.0f;
        }
    }
    partial[tid] = s;
    __syncthreads();
    for (int off = 1; off < 1024; off <<= 1) {
        int v = 0;
        if (tid >= off) v = partial[tid - off];
        __syncthreads();
        partial[tid] += v;
        __syncthreads();
    }
    int run = (tid > 0) ? partial[tid - 1] : 0;
    for (int i = 0; i < chunk; i++) {
        int idx = start + i;
        if (idx < n) { offsets[idx] = run; run += counts[idx]; }
    }
    if (tid == 1023) offsets[n] = partial[1023];
}

// blocks [0, eb): CSR edge build.  blocks [eb, ...): features -> bf16 * inv_deg.
__global__ void build_feat(const int* __restrict__ src, const int* __restrict__ dst,
                           const int* __restrict__ offsets, int* __restrict__ cursor,
                           int* __restrict__ ssrc, const float* __restrict__ features,
                           const float* __restrict__ inv, uint16_t* __restrict__ fbf,
                           int E, int eb, int N) {
    int b = blockIdx.x;
    if (b < eb) {
        int e = b * 256 + threadIdx.x;
        if (e < E) {
            int d = dst[e];
            int pos = offsets[d] + atomicAdd(&cursor[d], 1);
            ssrc[pos] = src[e];
        }
        return;
    }
    int idx = (b - eb) * 256 + threadIdx.x;
    int nc = N * (INF / 4);
    if (idx < nc) {
        int base = idx * 4;
        int row = base >> 7;                // /128
        float s = inv[row];
        float4 v = *(const float4*)&features[base];
        ushort4 o;
        o.x = f2bf(v.x * s); o.y = f2bf(v.y * s);
        o.z = f2bf(v.z * s); o.w = f2bf(v.w * s);
        *(ushort4*)&fbf[base] = o;
    }
}

// ---------------- fused layer 1: aggregate(128-wide) + GEMM K=128 ----------------
// 8 waves, ONE node per wave. LDS A-tile 16 rows (top 8 zeroed), XOR-swizzled.
__global__ __launch_bounds__(512) void fused_l1(
    const uint16_t* __restrict__ hs, const int* __restrict__ offsets,
    const int* __restrict__ ssrc, const uint16_t* __restrict__ Bsw,
    const float* __restrict__ bias, const float* __restrict__ inv,
    uint16_t* __restrict__ C, int M) {
    __shared__ uint16_t At[16 * INF];      // 4 KB, rows 8-15 zeroed
    const int tid = threadIdx.x;
    const int lane = tid & 63, wid = tid >> 6;
    if (tid < 128) {
        uint4 z = {0, 0, 0, 0};
        *(uint4*)((char*)At + 2048 + tid * 16) = z;
    }
    {   // aggregate: wave quarters, 4 edges in flight, node = blk*8 + wid
        const int q = lane >> 4, l16 = lane & 15;
        const size_t col = (size_t)l16 * 8;
        const int rt = wid;
        const int node = blockIdx.x * TM + rt;
        float a0 = 0, a1 = 0, a2 = 0, a3 = 0, a4 = 0, a5 = 0, a6 = 0, a7 = 0;
        if (node < M) {
            const int beg = offsets[node], end = offsets[node + 1];
            int e = beg + q;
            for (; e + 4 < end; e += 8) {
                int s0 = ssrc[e], s1 = ssrc[e + 4];
                uint4 r0 = *(const uint4*)&hs[(size_t)s0 * INF + col];
                uint4 r1 = *(const uint4*)&hs[(size_t)s1 * INF + col];
                a0 += bf_lo(r0.x) + bf_lo(r1.x); a1 += bf_hi(r0.x) + bf_hi(r1.x);
                a2 += bf_lo(r0.y) + bf_lo(r1.y); a3 += bf_hi(r0.y) + bf_hi(r1.y);
                a4 += bf_lo(r0.z) + bf_lo(r1.z); a5 += bf_hi(r0.z) + bf_hi(r1.z);
                a6 += bf_lo(r0.w) + bf_lo(r1.w); a7 += bf_hi(r0.w) + bf_hi(r1.w);
            }
            for (; e < end; e += 4) {
                uint4 t = *(const uint4*)&hs[(size_t)ssrc[e] * INF + col];
                a0 += bf_lo(t.x); a1 += bf_hi(t.x); a2 += bf_lo(t.y); a3 += bf_hi(t.y);
                a4 += bf_lo(t.z); a5 += bf_hi(t.z); a6 += bf_lo(t.w); a7 += bf_hi(t.w);
            }
        }
        a0 += __shfl_down(a0, 16, 64); a1 += __shfl_down(a1, 16, 64);
        a2 += __shfl_down(a2, 16, 64); a3 += __shfl_down(a3, 16, 64);
        a4 += __shfl_down(a4, 16, 64); a5 += __shfl_down(a5, 16, 64);
        a6 += __shfl_down(a6, 16, 64); a7 += __shfl_down(a7, 16, 64);
        a0 += __shfl_down(a0, 32, 64); a1 += __shfl_down(a1, 32, 64);
        a2 += __shfl_down(a2, 32, 64); a3 += __shfl_down(a3, 32, 64);
        a4 += __shfl_down(a4, 32, 64); a5 += __shfl_down(a5, 32, 64);
        a6 += __shfl_down(a6, 32, 64); a7 += __shfl_down(a7, 32, 64);
        if (lane < 16) {
            uint4 o;
            o.x = pack2(a0, a1); o.y = pack2(a2, a3);
            o.z = pack2(a4, a5); o.w = pack2(a6, a7);
            const int byte = (rt * 256 + l16 * 16) ^ ((rt & 7) << 4);
            *(uint4*)((char*)At + byte) = o;
        }
    }
    __syncthreads();
    // GEMM: wave wid handles cols [wid*32, wid*32+32); rows 0-7 valid
    const int quad = lane >> 4, l16 = lane & 15;
    const int n0 = wid * 32;
    const int xr = (l16 & 7) << 4;
    f32x4 acc00 = {0, 0, 0, 0}, acc01 = {0, 0, 0, 0};
#pragma unroll
    for (int p = 0; p < INF / 32; p++) {
        bf16x8 a0 = *(const bf16x8*)((const char*)At + ((l16 * 256 + p * 64 + quad * 16) ^ xr));
        bf16x8 b0 = *(const bf16x8*)(Bsw + ((size_t)p * 256 + n0 + l16) * 32 + quad * 8);
        bf16x8 b1 = *(const bf16x8*)(Bsw + ((size_t)p * 256 + n0 + 16 + l16) * 32 + quad * 8);
        acc00 = __builtin_amdgcn_mfma_f32_16x16x32_bf16(a0, b0, acc00, 0, 0, 0);
        acc01 = __builtin_amdgcn_mfma_f32_16x16x32_bf16(a0, b1, acc01, 0, 0, 0);
    }
    const int col0 = n0 + l16, col1 = col0 + 16;
    const float bv0 = bias[col0], bv1 = bias[col1];
#pragma unroll
    for (int reg = 0; reg < 4; reg++) {
        int r = quad * 4 + reg;
        if (r < 8) {
            int row = blockIdx.x * TM + r;
            if (row < M) {
                float s = inv[row];
                C[(size_t)row * 256 + col0] = f2bf(fmaxf(acc00[reg] + bv0, 0.f) * s);
                C[(size_t)row * 256 + col1] = f2bf(fmaxf(acc01[reg] + bv1, 0.f) * s);
            }
        }
    }
}

// ---------------- fused layer 2: aggregate(256-wide) + GEMM K=256 ----------------
__global__ __launch_bounds__(512) void fused_l2(
    const uint16_t* __restrict__ hs, const int* __restrict__ offsets,
    const int* __restrict__ ssrc, const uint16_t* __restrict__ Bsw,
    const float* __restrict__ bias, const float* __restrict__ inv,
    uint16_t* __restrict__ C, int M) {
    __shared__ uint16_t At[16 * HIDF];     // 8 KB, rows 8-15 zeroed
    const int tid = threadIdx.x;
    const int lane = tid & 63, wid = tid >> 6;
    if (tid < 256) {
        uint4 z = {0, 0, 0, 0};
        *(uint4*)((char*)At + 4096 + tid * 16) = z;
    }
    {   // aggregate: wave halves, 8-edge unroll, node = blk*8 + wid
        const int half = lane >> 5, l32 = lane & 31;
        const size_t col = (size_t)l32 * 8;
        const int rt = wid;
        const int node = blockIdx.x * TM + rt;
        float a0 = 0, a1 = 0, a2 = 0, a3 = 0, a4 = 0, a5 = 0, a6 = 0, a7 = 0;
        if (node < M) {
            const int beg = offsets[node], end = offsets[node + 1];
            int e = beg + half;
            for (; e + 6 < end; e += 8) {
                int s0 = ssrc[e], s1 = ssrc[e + 2], s2 = ssrc[e + 4], s3 = ssrc[e + 6];
                uint4 r0 = *(const uint4*)&hs[(size_t)s0 * 256 + col];
                uint4 r1 = *(const uint4*)&hs[(size_t)s1 * 256 + col];
                uint4 r2 = *(const uint4*)&hs[(size_t)s2 * 256 + col];
                uint4 r3 = *(const uint4*)&hs[(size_t)s3 * 256 + col];
                a0 += bf_lo(r0.x) + bf_lo(r1.x) + bf_lo(r2.x) + bf_lo(r3.x);
                a1 += bf_hi(r0.x) + bf_hi(r1.x) + bf_hi(r2.x) + bf_hi(r3.x);
                a2 += bf_lo(r0.y) + bf_lo(r1.y) + bf_lo(r2.y) + bf_lo(r3.y);
                a3 += bf_hi(r0.y) + bf_hi(r1.y) + bf_hi(r2.y) + bf_hi(r3.y);
                a4 += bf_lo(r0.z) + bf_lo(r1.z) + bf_lo(r2.z) + bf_lo(r3.z);
                a5 += bf_hi(r0.z) + bf_hi(r1.z) + bf_hi(r2.z) + bf_hi(r3.z);
                a6 += bf_lo(r0.w) + bf_lo(r1.w) + bf_lo(r2.w) + bf_lo(r3.w);
                a7 += bf_hi(r0.w) + bf_hi(r1.w) + bf_hi(r2.w) + bf_hi(r3.w);
            }
            for (; e < end; e += 2) {
                uint4 t = *(const uint4*)&hs[(size_t)ssrc[e] * 256 + col];
                a0 += bf_lo(t.x); a1 += bf_hi(t.x); a2 += bf_lo(t.y); a3 += bf_hi(t.y);
                a4 += bf_lo(t.z); a5 += bf_hi(t.z); a6 += bf_lo(t.w); a7 += bf_hi(t.w);
            }
        }
        a0 += __shfl_down(a0, 32, 64); a1 += __shfl_down(a1, 32, 64);
        a2 += __shfl_down(a2, 32, 64); a3 += __shfl_down(a3, 32, 64);
        a4 += __shfl_down(a4, 32, 64); a5 += __shfl_down(a5, 32, 64);
        a6 += __shfl_down(a6, 32, 64); a7 += __shfl_down(a7, 32, 64);
        if (half == 0) {
            uint4 o;
            o.x = pack2(a0, a1); o.y = pack2(a2, a3);
            o.z = pack2(a4, a5); o.w = pack2(a6, a7);
            const int byte = (rt * 512 + l32 * 16) ^ ((rt & 7) << 4);
            *(uint4*)((char*)At + byte) = o;
        }
    }
    __syncthreads();
    const int quad = lane >> 4, l16 = lane & 15;
    const int n0 = wid * 32;
    const int xr = (l16 & 7) << 4;
    f32x4 acc00 = {0, 0, 0, 0}, acc01 = {0, 0, 0, 0};
#pragma unroll
    for (int p = 0; p < HIDF / 32; p++) {
        bf16x8 a0 = *(const bf16x8*)((const char*)At + ((l16 * 512 + p * 64 + quad * 16) ^ xr));
        bf16x8 b0 = *(const bf16x8*)(Bsw + ((size_t)p * 256 + n0 + l16) * 32 + quad * 8);
        bf16x8 b1 = *(const bf16x8*)(Bsw + ((size_t)p * 256 + n0 + 16 + l16) * 32 + quad * 8);
        acc00 = __builtin_amdgcn_mfma_f32_16x16x32_bf16(a0, b0, acc00, 0, 0, 0);
        acc01 = __builtin_amdgcn_mfma_f32_16x16x32_bf16(a0, b1, acc01, 0, 0, 0);
    }
    const int col0 = n0 + l16, col1 = col0 + 16;
    const float bv0 = bias[col0], bv1 = bias[col1];
#pragma unroll
    for (int reg = 0; reg < 4; reg++) {
        int r = quad * 4 + reg;
        if (r < 8) {
            int row = blockIdx.x * TM + r;
            if (row < M) {
                float s = inv[row];
                C[(size_t)row * 256 + col0] = f2bf(fmaxf(acc00[reg] + bv0, 0.f) * s);
                C[(size_t)row * 256 + col1] = f2bf(fmaxf(acc01[reg] + bv1, 0.f) * s);
            }
        }
    }
}

// ---------------- fused layer 3 + both heads (pi plain store, colsum atomics) ----------------
__global__ __launch_bounds__(512) void fused_l3(
    const uint16_t* __restrict__ hs, const int* __restrict__ offsets,
    const int* __restrict__ ssrc, const uint16_t* __restrict__ Bsw,
    const float* __restrict__ b3, const float* __restrict__ Wp,
    const float* __restrict__ bp, float* __restrict__ pi_out,
    float* __restrict__ colsum, int M) {
    __shared__ uint16_t At[16 * HIDF];     // 8 KB, rows 8-15 zeroed
    __shared__ float pi_lds[TM][8];
    const int tid = threadIdx.x;
    const int lane = tid & 63, wid = tid >> 6;
    if (tid < 256) {
        uint4 z = {0, 0, 0, 0};
        *(uint4*)((char*)At + 4096 + tid * 16) = z;
    }
    {   // aggregate h2 (identical structure to l2)
        const int half = lane >> 5, l32 = lane & 31;
        const size_t col = (size_t)l32 * 8;
        const int rt = wid;
        const int node = blockIdx.x * TM + rt;
        float a0 = 0, a1 = 0, a2 = 0, a3 = 0, a4 = 0, a5 = 0, a6 = 0, a7 = 0;
        if (node < M) {
            const int beg = offsets[node], end = offsets[node + 1];
            int e = beg + half;
            for (; e + 6 < end; e += 8) {
                int s0 = ssrc[e], s1 = ssrc[e + 2], s2 = ssrc[e + 4], s3 = ssrc[e + 6];
                uint4 r0 = *(const uint4*)&hs[(size_t)s0 * 256 + col];
                uint4 r1 = *(const uint4*)&hs[(size_t)s1 * 256 + col];
                uint4 r2 = *(const uint4*)&hs[(size_t)s2 * 256 + col];
                uint4 r3 = *(const uint4*)&hs[(size_t)s3 * 256 + col];
                a0 += bf_lo(r0.x) + bf_lo(r1.x) + bf_lo(r2.x) + bf_lo(r3.x);
                a1 += bf_hi(r0.x) + bf_hi(r1.x) + bf_hi(r2.x) + bf_hi(r3.x);
                a2 += bf_lo(r0.y) + bf_lo(r1.y) + bf_lo(r2.y) + bf_lo(r3.y);
                a3 += bf_hi(r0.y) + bf_hi(r1.y) + bf_hi(r2.y) + bf_hi(r3.y);
                a4 += bf_lo(r0.z) + bf_lo(r1.z) + bf_lo(r2.z) + bf_lo(r3.z);
                a5 += bf_hi(r0.z) + bf_hi(r1.z) + bf_hi(r2.z) + bf_hi(r3.z);
                a6 += bf_lo(r0.w) + bf_lo(r1.w) + bf_lo(r2.w) + bf_lo(r3.w);
                a7 += bf_hi(r0.w) + bf_hi(r1.w) + bf_hi(r2.w) + bf_hi(r3.w);
            }
            for (; e < end; e += 2) {
                uint4 t = *(const uint4*)&hs[(size_t)ssrc[e] * 256 + col];
                a0 += bf_lo(t.x); a1 += bf_hi(t.x); a2 += bf_lo(t.y); a3 += bf_hi(t.y);
                a4 += bf_lo(t.z); a5 += bf_hi(t.z); a6 += bf_lo(t.w); a7 += bf_hi(t.w);
            }
        }
        a0 += __shfl_down(a0, 32, 64); a1 += __shfl_down(a1, 32, 64);
        a2 += __shfl_down(a2, 32, 64); a3 += __shfl_down(a3, 32, 64);
        a4 += __shfl_down(a4, 32, 64); a5 += __shfl_down(a5, 32, 64);
        a6 += __shfl_down(a6, 32, 64); a7 += __shfl_down(a7, 32, 64);
        if (half == 0) {
            uint4 o;
            o.x = pack2(a0, a1); o.y = pack2(a2, a3);
            o.z = pack2(a4, a5); o.w = pack2(a6, a7);
            const int byte = (rt * 512 + l32 * 16) ^ ((rt & 7) << 4);
            *(uint4*)((char*)At + byte) = o;
        }
    }
    __syncthreads();
    const int quad = lane >> 4, l16 = lane & 15;
    const int n0 = wid * 32;
    const int xr = (l16 & 7) << 4;
    f32x4 acc00 = {0, 0, 0, 0}, acc01 = {0, 0, 0, 0};
#pragma unroll
    for (int p = 0; p < HIDF / 32; p++) {
        bf16x8 a0 = *(const bf16x8*)((const char*)At + ((l16 * 512 + p * 64 + quad * 16) ^ xr));
        bf16x8 b0 = *(const bf16x8*)(Bsw + ((size_t)p * 256 + n0 + l16) * 32 + quad * 8);
        bf16x8 b1 = *(const bf16x8*)(Bsw + ((size_t)p * 256 + n0 + 16 + l16) * 32 + quad * 8);
        acc00 = __builtin_amdgcn_mfma_f32_16x16x32_bf16(a0, b0, acc00, 0, 0, 0);
        acc01 = __builtin_amdgcn_mfma_f32_16x16x32_bf16(a0, b1, acc01, 0, 0, 0);
    }
    const int col0 = n0 + l16, col1 = col0 + 16;
    const float bv0 = b3[col0], bv1 = b3[col1];
    const float wp0 = Wp[col0], wp1 = Wp[col1];
    float cs0 = 0.f, cs1 = 0.f;
#pragma unroll
    for (int reg = 0; reg < 4; reg++) {
        int r = quad * 4 + reg;
        int row = blockIdx.x * TM + r;
        bool ok = (r < 8) && (row < M);
        float v00 = acc00[reg] + bv0, v01 = acc01[reg] + bv1;
        if (ok) { cs0 += v00; cs1 += v01; }
        float p0 = v00 * wp0 + v01 * wp1;
#pragma unroll
        for (int m = 1; m < 16; m <<= 1) p0 += __shfl_xor(p0, m, 64);
        if (l16 == 0 && ok) pi_lds[r][wid] = p0;
    }
    cs0 += __shfl_xor(cs0, 16, 64); cs0 += __shfl_xor(cs0, 32, 64);
    cs1 += __shfl_xor(cs1, 16, 64); cs1 += __shfl_xor(cs1, 32, 64);
    if (quad == 0) {
        atomicAdd(&colsum[col0], cs0);
        atomicAdd(&colsum[col1], cs1);
    }
    __syncthreads();
    if (tid < TM) {
        int row = blockIdx.x * TM + tid;
        if (row < M) {
            float s = 0.f;
#pragma unroll
            for (int w = 0; w < 8; w++) s += pi_lds[tid][w];
            pi_out[row] = s + bp[0];
        }
    }
}

// ---------------- V head finisher ----------------
__global__ void v_kernel(const float* __restrict__ colsum, const float* __restrict__ Wv,
                         const float* __restrict__ bv, float* __restrict__ out, float invN) {
    int lane = threadIdx.x;  // 64
    float v = 0.0f;
#pragma unroll
    for (int i = 0; i < 4; i++) v += colsum[lane + 64 * i] * Wv[lane + 64 * i];
#pragma unroll
    for (int o = 32; o > 0; o >>= 1) v += __shfl_down(v, o, 64);
    if (lane == 0) out[0] = v * invN + bv[0];
}

// ---------------- launch ----------------

extern "C" void kernel_launch(void* const* d_in, const int* in_sizes, int n_in,
                              void* d_out, int out_size, void* d_ws, size_t ws_size,
                              hipStream_t stream) {
    const float* features = (const float*)d_in[0];
    const int*   src      = (const int*)d_in[1];
    const int*   dst      = (const int*)d_in[2];
    const float* W1 = (const float*)d_in[3];
    const float* b1 = (const float*)d_in[4];
    const float* W2 = (const float*)d_in[5];
    const float* b2 = (const float*)d_in[6];
    const float* W3 = (const float*)d_in[7];
    const float* b3 = (const float*)d_in[8];
    const float* Wp = (const float*)d_in[9];
    const float* bp = (const float*)d_in[10];
    const float* Wv = (const float*)d_in[11];
    const float* bv = (const float*)d_in[12];
    float* out = (float*)d_out;

    const int N = in_sizes[0] / INF;   // 10000
    const int E = in_sizes[1];         // 320000

    char* p = (char*)d_ws;
    auto alloc = [&](size_t bytes) -> void* {
        void* r = (void*)p;
        p += (bytes + 511) & ~(size_t)511;
        return r;
    };
    // zero-region first (single memset): odeg, counts, cursor, colsum
    int*      odeg    = (int*)alloc((size_t)N * 4);
    int*      counts  = (int*)alloc((size_t)N * 4);
    int*      cursor  = (int*)alloc((size_t)N * 4);
    float*    colsum  = (float*)alloc(HIDF * 4);
    size_t zero_bytes = (size_t)(p - (char*)d_ws);
    // rest
    int*      offsets = (int*)alloc((size_t)(N + 1) * 4);
    int*      ssrc    = (int*)alloc((size_t)E * 4);
    float*    invd    = (float*)alloc((size_t)N * 4);
    uint16_t* fbf     = (uint16_t*)alloc((size_t)N * INF * 2);
    uint16_t* h1      = (uint16_t*)alloc((size_t)N * HIDF * 2);
    uint16_t* h2      = (uint16_t*)alloc((size_t)N * HIDF * 2);
    uint16_t* W1s     = (uint16_t*)alloc((size_t)INF * HIDF * 2);
    uint16_t* W2s     = (uint16_t*)alloc((size_t)HIDF * HIDF * 2);
    uint16_t* W3s     = (uint16_t*)alloc((size_t)HIDF * HIDF * 2);

    hipMemsetAsync(d_ws, 0, zero_bytes, stream);

    const int eb = (E + 255) / 256;
    const int wb = (INF * HIDF + 2 * HIDF * HIDF + 255) / 256;
    hist_prepw<<<eb + wb, 256, 0, stream>>>(src, dst, odeg, counts,
                                            W1, W2, W3, W1s, W2s, W3s, E, eb);
    scan_kernel<<<1, 1024, 0, stream>>>(counts, offsets, odeg, invd, N);
    const int fb = (N * (INF / 4) + 255) / 256;
    build_feat<<<eb + fb, 256, 0, stream>>>(src, dst, offsets, cursor, ssrc,
                                            features, invd, fbf, E, eb, N);

    const int nblk = (N + TM - 1) / TM;   // 1250
    fused_l1<<<nblk, 512, 0, stream>>>(fbf, offsets, ssrc, W1s, b1, invd, h1, N);
    fused_l2<<<nblk, 512, 0, stream>>>(h1, offsets, ssrc, W2s, b2, invd, h2, N);
    fused_l3<<<nblk, 512, 0, stream>>>(h2, offsets, ssrc, W3s, b3, Wp, bp,
                                       out, colsum, N);

    v_kernel<<<1, 64, 0, stream>>>(colsum, Wv, bv, out + N, 1.0f / (float)N);
}

// Round 5
// 243.297 us; speedup vs baseline: 3.3907x; 1.0191x over previous
//
#include <hip/hip_runtime.h>
#include <stdint.h>

// GCN: 3x GraphConv (left norm) + heads, bf16 internal / fp32 accumulate.
// This revision: fused TM=8 layers with FULLY-PREDICATED 8-deep gather pipeline
// (no serial tail; OOB edges read a zeroed dummy row -> +0.0). Wave-quarters
// for 128-wide (l1), wave-halves for 256-wide (l2/l3), 8 row-loads in flight.
// 7 dispatches; no device fences (cost ~200us on gfx950 per-XCD L2 writeback).

#define INF 128
#define HIDF 256
#define TM 8     // rows per fused block (one node per wave)

typedef __attribute__((ext_vector_type(8))) short bf16x8;   // 8 bf16 (4 VGPRs)
typedef __attribute__((ext_vector_type(4))) float f32x4;

__device__ __forceinline__ float bf_lo(uint32_t u) {
    union { uint32_t i; float f; } x; x.i = u << 16; return x.f;
}
__device__ __forceinline__ float bf_hi(uint32_t u) {
    union { uint32_t i; float f; } x; x.i = u & 0xffff0000u; return x.f;
}
__device__ __forceinline__ uint16_t f2bf(float f) {   // round-to-nearest-even
    union { float f; uint32_t i; } x; x.f = f;
    uint32_t r = x.i + 0x7fffu + ((x.i >> 16) & 1u);
    return (uint16_t)(r >> 16);
}
__device__ __forceinline__ uint32_t pack2(float a, float b) {
    return (uint32_t)f2bf(a) | ((uint32_t)f2bf(b) << 16);
}

// ---------------- preprocessing ----------------

// blocks [0, eb): degree histograms.  blocks [eb, ...): W1/W2/W3 swizzle.
// Bsw layout: [k/32][n][k%32]
__global__ void hist_prepw(const int* __restrict__ src, const int* __restrict__ dst,
                           int* __restrict__ odeg, int* __restrict__ counts,
                           const float* __restrict__ W1, const float* __restrict__ W2,
                           const float* __restrict__ W3,
                           uint16_t* __restrict__ W1s, uint16_t* __restrict__ W2s,
                           uint16_t* __restrict__ W3s, int E, int eb) {
    int b = blockIdx.x;
    if (b < eb) {
        int e = b * 256 + threadIdx.x;
        if (e < E) {
            atomicAdd(&odeg[src[e]], 1);
            atomicAdd(&counts[dst[e]], 1);
        }
        return;
    }
    int idx = (b - eb) * 256 + threadIdx.x;
    if (idx < INF * HIDF) {
        int k = idx >> 8, n = idx & 255;
        W1s[((size_t)(k >> 5) * 256 + n) * 32 + (k & 31)] = f2bf(W1[idx]);
        return;
    }
    idx -= INF * HIDF;
    if (idx < HIDF * HIDF) {
        int k = idx >> 8, n = idx & 255;
        W2s[((size_t)(k >> 5) * 256 + n) * 32 + (k & 31)] = f2bf(W2[idx]);
        return;
    }
    idx -= HIDF * HIDF;
    if (idx < HIDF * HIDF) {
        int k = idx >> 8, n = idx & 255;
        W3s[((size_t)(k >> 5) * 256 + n) * 32 + (k & 31)] = f2bf(W3[idx]);
    }
}

// scan of counts -> offsets[0..n]; also computes inv_deg
__global__ __launch_bounds__(1024) void scan_kernel(const int* __restrict__ counts,
                                                    int* __restrict__ offsets,
                                                    const int* __restrict__ odeg,
                                                    float* __restrict__ inv, int n) {
    __shared__ int partial[1024];
    int tid = threadIdx.x;
    int chunk = (n + 1023) / 1024;
    int start = tid * chunk;
    int s = 0;
    for (int i = 0; i < chunk; i++) {
        int idx = start + i;
        if (idx < n) {
            s += counts[idx];
            int d = odeg[idx];
            inv[idx] = d > 0 ? 1.0f / (float)d : 0.0f;
        }
    }
    partial[tid] = s;
    __syncthreads();
    for (int off = 1; off < 1024; off <<= 1) {
        int v = 0;
        if (tid >= off) v = partial[tid - off];
        __syncthreads();
        partial[tid] += v;
        __syncthreads();
    }
    int run = (tid > 0) ? partial[tid - 1] : 0;
    for (int i = 0; i < chunk; i++) {
        int idx = start + i;
        if (idx < n) { offsets[idx] = run; run += counts[idx]; }
    }
    if (tid == 1023) offsets[n] = partial[1023];
}

// blocks [0, eb): CSR edge build.  blocks [eb, ...): features -> bf16 * inv_deg.
__global__ void build_feat(const int* __restrict__ src, const int* __restrict__ dst,
                           const int* __restrict__ offsets, int* __restrict__ cursor,
                           int* __restrict__ ssrc, const float* __restrict__ features,
                           const float* __restrict__ inv, uint16_t* __restrict__ fbf,
                           int E, int eb, int N) {
    int b = blockIdx.x;
    if (b < eb) {
        int e = b * 256 + threadIdx.x;
        if (e < E) {
            int d = dst[e];
            int pos = offsets[d] + atomicAdd(&cursor[d], 1);
            ssrc[pos] = src[e];
        }
        return;
    }
    int idx = (b - eb) * 256 + threadIdx.x;
    int nc = N * (INF / 4);
    if (idx < nc) {
        int base = idx * 4;
        int row = base >> 7;                // /128
        float s = inv[row];
        float4 v = *(const float4*)&features[base];
        ushort4 o;
        o.x = f2bf(v.x * s); o.y = f2bf(v.y * s);
        o.z = f2bf(v.z * s); o.w = f2bf(v.w * s);
        *(ushort4*)&fbf[base] = o;
    }
}

// ---------------- fused layer 1: aggregate(128-wide) + GEMM K=128 ----------------
// 8 waves, ONE node per wave. Quarter-waves, predicated 8-deep gather pipeline.
__global__ __launch_bounds__(512) void fused_l1(
    const uint16_t* __restrict__ hs, const int* __restrict__ offsets,
    const int* __restrict__ ssrc, const uint16_t* __restrict__ zrow,
    const uint16_t* __restrict__ Bsw,
    const float* __restrict__ bias, const float* __restrict__ inv,
    uint16_t* __restrict__ C, int M) {
    __shared__ uint16_t At[16 * INF];      // 4 KB, rows 8-15 zeroed
    const int tid = threadIdx.x;
    const int lane = tid & 63, wid = tid >> 6;
    if (tid < 128) {
        uint4 z = {0, 0, 0, 0};
        *(uint4*)((char*)At + 2048 + tid * 16) = z;
    }
    {   // aggregate: quarters, stride 4, depth 8 (one iter covers 32 edge-slots)
        const int q = lane >> 4, l16 = lane & 15;
        const size_t col = (size_t)l16 * 8;
        const int rt = wid;
        const int node = blockIdx.x * TM + rt;
        float a0 = 0, a1 = 0, a2 = 0, a3 = 0, a4 = 0, a5 = 0, a6 = 0, a7 = 0;
        if (node < M) {
            const int beg = offsets[node], end = offsets[node + 1];
            const int last = end - 1;
            const uint16_t* __restrict__ hb = hs + col;
            const uint16_t* __restrict__ z8 = zrow + col;
            for (int e0 = beg + q; e0 < end; e0 += 32) {
                int i0 = ssrc[e0];
                int i1 = ssrc[min(e0 + 4, last)];
                int i2 = ssrc[min(e0 + 8, last)];
                int i3 = ssrc[min(e0 + 12, last)];
                int i4 = ssrc[min(e0 + 16, last)];
                int i5 = ssrc[min(e0 + 20, last)];
                int i6 = ssrc[min(e0 + 24, last)];
                int i7 = ssrc[min(e0 + 28, last)];
                uint4 r0 = *(const uint4*)&hb[(size_t)i0 * INF];
                uint4 r1 = *(const uint4*)((e0 + 4  < end) ? &hb[(size_t)i1 * INF] : z8);
                uint4 r2 = *(const uint4*)((e0 + 8  < end) ? &hb[(size_t)i2 * INF] : z8);
                uint4 r3 = *(const uint4*)((e0 + 12 < end) ? &hb[(size_t)i3 * INF] : z8);
                uint4 r4 = *(const uint4*)((e0 + 16 < end) ? &hb[(size_t)i4 * INF] : z8);
                uint4 r5 = *(const uint4*)((e0 + 20 < end) ? &hb[(size_t)i5 * INF] : z8);
                uint4 r6 = *(const uint4*)((e0 + 24 < end) ? &hb[(size_t)i6 * INF] : z8);
                uint4 r7 = *(const uint4*)((e0 + 28 < end) ? &hb[(size_t)i7 * INF] : z8);
                a0 += ((bf_lo(r0.x) + bf_lo(r1.x)) + (bf_lo(r2.x) + bf_lo(r3.x)))
                    + ((bf_lo(r4.x) + bf_lo(r5.x)) + (bf_lo(r6.x) + bf_lo(r7.x)));
                a1 += ((bf_hi(r0.x) + bf_hi(r1.x)) + (bf_hi(r2.x) + bf_hi(r3.x)))
                    + ((bf_hi(r4.x) + bf_hi(r5.x)) + (bf_hi(r6.x) + bf_hi(r7.x)));
                a2 += ((bf_lo(r0.y) + bf_lo(r1.y)) + (bf_lo(r2.y) + bf_lo(r3.y)))
                    + ((bf_lo(r4.y) + bf_lo(r5.y)) + (bf_lo(r6.y) + bf_lo(r7.y)));
                a3 += ((bf_hi(r0.y) + bf_hi(r1.y)) + (bf_hi(r2.y) + bf_hi(r3.y)))
                    + ((bf_hi(r4.y) + bf_hi(r5.y)) + (bf_hi(r6.y) + bf_hi(r7.y)));
                a4 += ((bf_lo(r0.z) + bf_lo(r1.z)) + (bf_lo(r2.z) + bf_lo(r3.z)))
                    + ((bf_lo(r4.z) + bf_lo(r5.z)) + (bf_lo(r6.z) + bf_lo(r7.z)));
                a5 += ((bf_hi(r0.z) + bf_hi(r1.z)) + (bf_hi(r2.z) + bf_hi(r3.z)))
                    + ((bf_hi(r4.z) + bf_hi(r5.z)) + (bf_hi(r6.z) + bf_hi(r7.z)));
                a6 += ((bf_lo(r0.w) + bf_lo(r1.w)) + (bf_lo(r2.w) + bf_lo(r3.w)))
                    + ((bf_lo(r4.w) + bf_lo(r5.w)) + (bf_lo(r6.w) + bf_lo(r7.w)));
                a7 += ((bf_hi(r0.w) + bf_hi(r1.w)) + (bf_hi(r2.w) + bf_hi(r3.w)))
                    + ((bf_hi(r4.w) + bf_hi(r5.w)) + (bf_hi(r6.w) + bf_hi(r7.w)));
            }
        }
        a0 += __shfl_down(a0, 16, 64); a1 += __shfl_down(a1, 16, 64);
        a2 += __shfl_down(a2, 16, 64); a3 += __shfl_down(a3, 16, 64);
        a4 += __shfl_down(a4, 16, 64); a5 += __shfl_down(a5, 16, 64);
        a6 += __shfl_down(a6, 16, 64); a7 += __shfl_down(a7, 16, 64);
        a0 += __shfl_down(a0, 32, 64); a1 += __shfl_down(a1, 32, 64);
        a2 += __shfl_down(a2, 32, 64); a3 += __shfl_down(a3, 32, 64);
        a4 += __shfl_down(a4, 32, 64); a5 += __shfl_down(a5, 32, 64);
        a6 += __shfl_down(a6, 32, 64); a7 += __shfl_down(a7, 32, 64);
        if (lane < 16) {
            uint4 o;
            o.x = pack2(a0, a1); o.y = pack2(a2, a3);
            o.z = pack2(a4, a5); o.w = pack2(a6, a7);
            const int byte = (rt * 256 + l16 * 16) ^ ((rt & 7) << 4);
            *(uint4*)((char*)At + byte) = o;
        }
    }
    __syncthreads();
    // GEMM: wave wid handles cols [wid*32, wid*32+32); rows 0-7 valid
    const int quad = lane >> 4, l16 = lane & 15;
    const int n0 = wid * 32;
    const int xr = (l16 & 7) << 4;
    f32x4 acc00 = {0, 0, 0, 0}, acc01 = {0, 0, 0, 0};
#pragma unroll
    for (int p = 0; p < INF / 32; p++) {
        bf16x8 a0 = *(const bf16x8*)((const char*)At + ((l16 * 256 + p * 64 + quad * 16) ^ xr));
        bf16x8 b0 = *(const bf16x8*)(Bsw + ((size_t)p * 256 + n0 + l16) * 32 + quad * 8);
        bf16x8 b1 = *(const bf16x8*)(Bsw + ((size_t)p * 256 + n0 + 16 + l16) * 32 + quad * 8);
        acc00 = __builtin_amdgcn_mfma_f32_16x16x32_bf16(a0, b0, acc00, 0, 0, 0);
        acc01 = __builtin_amdgcn_mfma_f32_16x16x32_bf16(a0, b1, acc01, 0, 0, 0);
    }
    const int col0 = n0 + l16, col1 = col0 + 16;
    const float bv0 = bias[col0], bv1 = bias[col1];
#pragma unroll
    for (int reg = 0; reg < 4; reg++) {
        int r = quad * 4 + reg;
        if (r < 8) {
            int row = blockIdx.x * TM + r;
            if (row < M) {
                float s = inv[row];
                C[(size_t)row * 256 + col0] = f2bf(fmaxf(acc00[reg] + bv0, 0.f) * s);
                C[(size_t)row * 256 + col1] = f2bf(fmaxf(acc01[reg] + bv1, 0.f) * s);
            }
        }
    }
}

// ---- shared 256-wide predicated aggregate (halves, stride 2, depth 8) ----
__device__ __forceinline__ void agg256(
    const uint16_t* __restrict__ hs, const int* __restrict__ offsets,
    const int* __restrict__ ssrc, const uint16_t* __restrict__ zrow,
    uint16_t* At, int node, int M, int lane, int rt) {
    const int half = lane >> 5, l32 = lane & 31;
    const size_t col = (size_t)l32 * 8;
    float a0 = 0, a1 = 0, a2 = 0, a3 = 0, a4 = 0, a5 = 0, a6 = 0, a7 = 0;
    if (node < M) {
        const int beg = offsets[node], end = offsets[node + 1];
        const int last = end - 1;
        const uint16_t* __restrict__ hb = hs + col;
        const uint16_t* __restrict__ z8 = zrow + col;
        for (int e0 = beg + half; e0 < end; e0 += 16) {
            int i0 = ssrc[e0];
            int i1 = ssrc[min(e0 + 2, last)];
            int i2 = ssrc[min(e0 + 4, last)];
            int i3 = ssrc[min(e0 + 6, last)];
            int i4 = ssrc[min(e0 + 8, last)];
            int i5 = ssrc[min(e0 + 10, last)];
            int i6 = ssrc[min(e0 + 12, last)];
            int i7 = ssrc[min(e0 + 14, last)];
            uint4 r0 = *(const uint4*)&hb[(size_t)i0 * 256];
            uint4 r1 = *(const uint4*)((e0 + 2  < end) ? &hb[(size_t)i1 * 256] : z8);
            uint4 r2 = *(const uint4*)((e0 + 4  < end) ? &hb[(size_t)i2 * 256] : z8);
            uint4 r3 = *(const uint4*)((e0 + 6  < end) ? &hb[(size_t)i3 * 256] : z8);
            uint4 r4 = *(const uint4*)((e0 + 8  < end) ? &hb[(size_t)i4 * 256] : z8);
            uint4 r5 = *(const uint4*)((e0 + 10 < end) ? &hb[(size_t)i5 * 256] : z8);
            uint4 r6 = *(const uint4*)((e0 + 12 < end) ? &hb[(size_t)i6 * 256] : z8);
            uint4 r7 = *(const uint4*)((e0 + 14 < end) ? &hb[(size_t)i7 * 256] : z8);
            a0 += ((bf_lo(r0.x) + bf_lo(r1.x)) + (bf_lo(r2.x) + bf_lo(r3.x)))
                + ((bf_lo(r4.x) + bf_lo(r5.x)) + (bf_lo(r6.x) + bf_lo(r7.x)));
            a1 += ((bf_hi(r0.x) + bf_hi(r1.x)) + (bf_hi(r2.x) + bf_hi(r3.x)))
                + ((bf_hi(r4.x) + bf_hi(r5.x)) + (bf_hi(r6.x) + bf_hi(r7.x)));
            a2 += ((bf_lo(r0.y) + bf_lo(r1.y)) + (bf_lo(r2.y) + bf_lo(r3.y)))
                + ((bf_lo(r4.y) + bf_lo(r5.y)) + (bf_lo(r6.y) + bf_lo(r7.y)));
            a3 += ((bf_hi(r0.y) + bf_hi(r1.y)) + (bf_hi(r2.y) + bf_hi(r3.y)))
                + ((bf_hi(r4.y) + bf_hi(r5.y)) + (bf_hi(r6.y) + bf_hi(r7.y)));
            a4 += ((bf_lo(r0.z) + bf_lo(r1.z)) + (bf_lo(r2.z) + bf_lo(r3.z)))
                + ((bf_lo(r4.z) + bf_lo(r5.z)) + (bf_lo(r6.z) + bf_lo(r7.z)));
            a5 += ((bf_hi(r0.z) + bf_hi(r1.z)) + (bf_hi(r2.z) + bf_hi(r3.z)))
                + ((bf_hi(r4.z) + bf_hi(r5.z)) + (bf_hi(r6.z) + bf_hi(r7.z)));
            a6 += ((bf_lo(r0.w) + bf_lo(r1.w)) + (bf_lo(r2.w) + bf_lo(r3.w)))
                + ((bf_lo(r4.w) + bf_lo(r5.w)) + (bf_lo(r6.w) + bf_lo(r7.w)));
            a7 += ((bf_hi(r0.w) + bf_hi(r1.w)) + (bf_hi(r2.w) + bf_hi(r3.w)))
                + ((bf_hi(r4.w) + bf_hi(r5.w)) + (bf_hi(r6.w) + bf_hi(r7.w)));
        }
    }
    a0 += __shfl_down(a0, 32, 64); a1 += __shfl_down(a1, 32, 64);
    a2 += __shfl_down(a2, 32, 64); a3 += __shfl_down(a3, 32, 64);
    a4 += __shfl_down(a4, 32, 64); a5 += __shfl_down(a5, 32, 64);
    a6 += __shfl_down(a6, 32, 64); a7 += __shfl_down(a7, 32, 64);
    if (half == 0) {
        uint4 o;
        o.x = pack2(a0, a1); o.y = pack2(a2, a3);
        o.z = pack2(a4, a5); o.w = pack2(a6, a7);
        const int byte = (rt * 512 + l32 * 16) ^ ((rt & 7) << 4);
        *(uint4*)((char*)At + byte) = o;
    }
}

// ---------------- fused layer 2: aggregate(256-wide) + GEMM K=256 ----------------
__global__ __launch_bounds__(512) void fused_l2(
    const uint16_t* __restrict__ hs, const int* __restrict__ offsets,
    const int* __restrict__ ssrc, const uint16_t* __restrict__ zrow,
    const uint16_t* __restrict__ Bsw,
    const float* __restrict__ bias, const float* __restrict__ inv,
    uint16_t* __restrict__ C, int M) {
    __shared__ uint16_t At[16 * HIDF];     // 8 KB, rows 8-15 zeroed
    const int tid = threadIdx.x;
    const int lane = tid & 63, wid = tid >> 6;
    if (tid < 256) {
        uint4 z = {0, 0, 0, 0};
        *(uint4*)((char*)At + 4096 + tid * 16) = z;
    }
    agg256(hs, offsets, ssrc, zrow, At, blockIdx.x * TM + wid, M, lane, wid);
    __syncthreads();
    const int quad = lane >> 4, l16 = lane & 15;
    const int n0 = wid * 32;
    const int xr = (l16 & 7) << 4;
    f32x4 acc00 = {0, 0, 0, 0}, acc01 = {0, 0, 0, 0};
#pragma unroll
    for (int p = 0; p < HIDF / 32; p++) {
        bf16x8 a0 = *(const bf16x8*)((const char*)At + ((l16 * 512 + p * 64 + quad * 16) ^ xr));
        bf16x8 b0 = *(const bf16x8*)(Bsw + ((size_t)p * 256 + n0 + l16) * 32 + quad * 8);
        bf16x8 b1 = *(const bf16x8*)(Bsw + ((size_t)p * 256 + n0 + 16 + l16) * 32 + quad * 8);
        acc00 = __builtin_amdgcn_mfma_f32_16x16x32_bf16(a0, b0, acc00, 0, 0, 0);
        acc01 = __builtin_amdgcn_mfma_f32_16x16x32_bf16(a0, b1, acc01, 0, 0, 0);
    }
    const int col0 = n0 + l16, col1 = col0 + 16;
    const float bv0 = bias[col0], bv1 = bias[col1];
#pragma unroll
    for (int reg = 0; reg < 4; reg++) {
        int r = quad * 4 + reg;
        if (r < 8) {
            int row = blockIdx.x * TM + r;
            if (row < M) {
                float s = inv[row];
                C[(size_t)row * 256 + col0] = f2bf(fmaxf(acc00[reg] + bv0, 0.f) * s);
                C[(size_t)row * 256 + col1] = f2bf(fmaxf(acc01[reg] + bv1, 0.f) * s);
            }
        }
    }
}

// ---------------- fused layer 3 + both heads (pi plain store, colsum atomics) ----------------
__global__ __launch_bounds__(512) void fused_l3(
    const uint16_t* __restrict__ hs, const int* __restrict__ offsets,
    const int* __restrict__ ssrc, const uint16_t* __restrict__ zrow,
    const uint16_t* __restrict__ Bsw,
    const float* __restrict__ b3, const float* __restrict__ Wp,
    const float* __restrict__ bp, float* __restrict__ pi_out,
    float* __restrict__ colsum, int M) {
    __shared__ uint16_t At[16 * HIDF];     // 8 KB, rows 8-15 zeroed
    __shared__ float pi_lds[TM][8];
    const int tid = threadIdx.x;
    const int lane = tid & 63, wid = tid >> 6;
    if (tid < 256) {
        uint4 z = {0, 0, 0, 0};
        *(uint4*)((char*)At + 4096 + tid * 16) = z;
    }
    agg256(hs, offsets, ssrc, zrow, At, blockIdx.x * TM + wid, M, lane, wid);
    __syncthreads();
    const int quad = lane >> 4, l16 = lane & 15;
    const int n0 = wid * 32;
    const int xr = (l16 & 7) << 4;
    f32x4 acc00 = {0, 0, 0, 0}, acc01 = {0, 0, 0, 0};
#pragma unroll
    for (int p = 0; p < HIDF / 32; p++) {
        bf16x8 a0 = *(const bf16x8*)((const char*)At + ((l16 * 512 + p * 64 + quad * 16) ^ xr));
        bf16x8 b0 = *(const bf16x8*)(Bsw + ((size_t)p * 256 + n0 + l16) * 32 + quad * 8);
        bf16x8 b1 = *(const bf16x8*)(Bsw + ((size_t)p * 256 + n0 + 16 + l16) * 32 + quad * 8);
        acc00 = __builtin_amdgcn_mfma_f32_16x16x32_bf16(a0, b0, acc00, 0, 0, 0);
        acc01 = __builtin_amdgcn_mfma_f32_16x16x32_bf16(a0, b1, acc01, 0, 0, 0);
    }
    const int col0 = n0 + l16, col1 = col0 + 16;
    const float bv0 = b3[col0], bv1 = b3[col1];
    const float wp0 = Wp[col0], wp1 = Wp[col1];
    float cs0 = 0.f, cs1 = 0.f;
#pragma unroll
    for (int reg = 0; reg < 4; reg++) {
        int r = quad * 4 + reg;
        int row = blockIdx.x * TM + r;
        bool ok = (r < 8) && (row < M);
        float v00 = acc00[reg] + bv0, v01 = acc01[reg] + bv1;
        if (ok) { cs0 += v00; cs1 += v01; }
        float p0 = v00 * wp0 + v01 * wp1;
#pragma unroll
        for (int m = 1; m < 16; m <<= 1) p0 += __shfl_xor(p0, m, 64);
        if (l16 == 0 && ok) pi_lds[r][wid] = p0;
    }
    cs0 += __shfl_xor(cs0, 16, 64); cs0 += __shfl_xor(cs0, 32, 64);
    cs1 += __shfl_xor(cs1, 16, 64); cs1 += __shfl_xor(cs1, 32, 64);
    if (quad == 0) {
        atomicAdd(&colsum[col0], cs0);
        atomicAdd(&colsum[col1], cs1);
    }
    __syncthreads();
    if (tid < TM) {
        int row = blockIdx.x * TM + tid;
        if (row < M) {
            float s = 0.f;
#pragma unroll
            for (int w = 0; w < 8; w++) s += pi_lds[tid][w];
            pi_out[row] = s + bp[0];
        }
    }
}

// ---------------- V head finisher ----------------
__global__ void v_kernel(const float* __restrict__ colsum, const float* __restrict__ Wv,
                         const float* __restrict__ bv, float* __restrict__ out, float invN) {
    int lane = threadIdx.x;  // 64
    float v = 0.0f;
#pragma unroll
    for (int i = 0; i < 4; i++) v += colsum[lane + 64 * i] * Wv[lane + 64 * i];
#pragma unroll
    for (int o = 32; o > 0; o >>= 1) v += __shfl_down(v, o, 64);
    if (lane == 0) out[0] = v * invN + bv[0];
}

// ---------------- launch ----------------

extern "C" void kernel_launch(void* const* d_in, const int* in_sizes, int n_in,
                              void* d_out, int out_size, void* d_ws, size_t ws_size,
                              hipStream_t stream) {
    const float* features = (const float*)d_in[0];
    const int*   src      = (const int*)d_in[1];
    const int*   dst      = (const int*)d_in[2];
    const float* W1 = (const float*)d_in[3];
    const float* b1 = (const float*)d_in[4];
    const float* W2 = (const float*)d_in[5];
    const float* b2 = (const float*)d_in[6];
    const float* W3 = (const float*)d_in[7];
    const float* b3 = (const float*)d_in[8];
    const float* Wp = (const float*)d_in[9];
    const float* bp = (const float*)d_in[10];
    const float* Wv = (const float*)d_in[11];
    const float* bv = (const float*)d_in[12];
    float* out = (float*)d_out;

    const int N = in_sizes[0] / INF;   // 10000
    const int E = in_sizes[1];         // 320000

    char* p = (char*)d_ws;
    auto alloc = [&](size_t bytes) -> void* {
        void* r = (void*)p;
        p += (bytes + 511) & ~(size_t)511;
        return r;
    };
    // zero-region first (single memset): odeg, counts, cursor, colsum, zrow
    int*      odeg    = (int*)alloc((size_t)N * 4);
    int*      counts  = (int*)alloc((size_t)N * 4);
    int*      cursor  = (int*)alloc((size_t)N * 4);
    float*    colsum  = (float*)alloc(HIDF * 4);
    uint16_t* zrow    = (uint16_t*)alloc(512);        // zeroed dummy row (OOB target)
    size_t zero_bytes = (size_t)(p - (char*)d_ws);
    // rest
    int*      offsets = (int*)alloc((size_t)(N + 1) * 4);
    int*      ssrc    = (int*)alloc((size_t)E * 4);
    float*    invd    = (float*)alloc((size_t)N * 4);
    uint16_t* fbf     = (uint16_t*)alloc((size_t)N * INF * 2);
    uint16_t* h1      = (uint16_t*)alloc((size_t)N * HIDF * 2);
    uint16_t* h2      = (uint16_t*)alloc((size_t)N * HIDF * 2);
    uint16_t* W1s     = (uint16_t*)alloc((size_t)INF * HIDF * 2);
    uint16_t* W2s     = (uint16_t*)alloc((size_t)HIDF * HIDF * 2);
    uint16_t* W3s     = (uint16_t*)alloc((size_t)HIDF * HIDF * 2);

    hipMemsetAsync(d_ws, 0, zero_bytes, stream);

    const int eb = (E + 255) / 256;
    const int wb = (INF * HIDF + 2 * HIDF * HIDF + 255) / 256;
    hist_prepw<<<eb + wb, 256, 0, stream>>>(src, dst, odeg, counts,
                                            W1, W2, W3, W1s, W2s, W3s, E, eb);
    scan_kernel<<<1, 1024, 0, stream>>>(counts, offsets, odeg, invd, N);
    const int fb = (N * (INF / 4) + 255) / 256;
    build_feat<<<eb + fb, 256, 0, stream>>>(src, dst, offsets, cursor, ssrc,
                                            features, invd, fbf, E, eb, N);

    const int nblk = (N + TM - 1) / TM;   // 1250
    fused_l1<<<nblk, 512, 0, stream>>>(fbf, offsets, ssrc, zrow, W1s, b1, invd, h1, N);
    fused_l2<<<nblk, 512, 0, stream>>>(h1, offsets, ssrc, zrow, W2s, b2, invd, h2, N);
    fused_l3<<<nblk, 512, 0, stream>>>(h2, offsets, ssrc, zrow, W3s, b3, Wp, bp,
                                       out, colsum, N);

    v_kernel<<<1, 64, 0, stream>>>(colsum, Wv, bv, out + N, 1.0f / (float)N);
}